// Round 4
// baseline (601.369 us; speedup 1.0000x reference)
//
#include <hip/hip_runtime.h>

// ---------------- problem constants ----------------
#define N_NODES 30000
#define N_EDGES 480000
#define E_TOT   510000        // edges + self loops
#define BQ      4096
#define IN_DIM  1281
#define KP1     1344          // 1281 padded to mult of 64 (pack tile) & 32 (gemm)
#define NKG     (KP1/64)      // 21 col-groups in pack_x
#define MP      30080         // 30000 padded to mult of 128
#define NBM     235           // MP/128
#define TS1     (KP1*128)     // A'/B' tile stride (shorts), layer 1
#define TS2     (256*128)     // tile stride, layer 2

// merged-grid block counts
#define NB_PXS  NBM               // 235 pack_x row-stripe blocks (kg-loop inside)
#define NB_PW1  ((KP1/8)*4)       // 672 pack_w layer-1 blocks
#define NB_PW2  ((256/8)*4)       // 128 pack_w layer-2 blocks
#define NB_SC   ((E_TOT+255)/256) // 1993 scatter / edge_count blocks
#define NB_PREP2 (NB_PXS+NB_PW1+NB_PW2+NB_SC)
#define NB_GEMM 940               // NBM*4 tiles (128x128)

typedef __attribute__((ext_vector_type(8))) short bf16x8;
typedef __attribute__((ext_vector_type(4))) float f32x4;

__device__ __forceinline__ short f2bf(float f) {
    unsigned int u = __builtin_bit_cast(unsigned int, f);
    u += 0x7fffu + ((u >> 16) & 1u);       // RNE
    return (short)(u >> 16);
}

__device__ __forceinline__ float bf2f(short s) {
    unsigned int u = ((unsigned int)(unsigned short)s) << 16;
    return __builtin_bit_cast(float, u);
}

__device__ __forceinline__ void async16(void* lds, const void* g) {
    __builtin_amdgcn_global_load_lds(
        (const __attribute__((address_space(1))) void*)g,
        (__attribute__((address_space(3))) void*)lds, 16, 0, 0);
}

__device__ __forceinline__ float elu1(float x) {
    return x > 0.f ? x : __expf(x) - 1.f;
}

__device__ __forceinline__ float lrelu(float x) {
    return x > 0.f ? x : 0.2f * x;
}

// ---------------- pack bodies ----------------
// R4: one block per 128-row stripe, looping all 21 kg chunks so the block
// streams its 656 KB row-slab sequentially (DRAM page locality) instead of
// 21 scattered blocks nibbling 256 B per row. 32 loads in flight per wave.
__device__ __forceinline__ void pack_x_stripe_body(int mt, short* L /*[128][72]*/,
                                                   const float* __restrict__ x,
                                                   short* __restrict__ A) {
    short (*Lx)[72] = (short(*)[72])L;
    const int t = threadIdx.x;
    const int wave = t >> 6, lane = t & 63;
    const int m0 = mt * 128;
    for (int kg = 0; kg < NKG; ++kg) {
        const int col = kg * 64 + lane;
        const bool cok = col < IN_DIM;
        const float* xcol = x + col;
        float v[32];
        #pragma unroll
        for (int j = 0; j < 32; ++j) {
            int ml = j * 4 + wave;
            int m = m0 + ml;
            v[j] = (cok && m < N_NODES) ? xcol[(size_t)m * IN_DIM] : 0.f;
        }
        #pragma unroll
        for (int j = 0; j < 32; ++j) {
            int ml = j * 4 + wave;
            Lx[ml][lane] = f2bf(v[j]);
        }
        __syncthreads();
        short* Atile = A + (size_t)mt * TS1 + (size_t)kg * 8 * 1024;
        #pragma unroll
        for (int pass = 0; pass < 4; ++pass) {
            int u = pass * 256 + t;          // 0..1023
            int tc = u >> 7, ml = u & 127;   // tc 0..7 (this kg's 8 kchunks)
            *(bf16x8*)(Atile + (size_t)tc * 1024 + ml * 8) = *(const bf16x8*)&Lx[ml][tc * 8];
        }
        __syncthreads();
    }
}

// W (K x 256 row-major, Wl|Wr) -> B'[bt][kchunk][n&127][k&7]; k-pad zeroed.
__device__ __forceinline__ void pack_w_body(int kc, int bt, short* L /*[8][128]*/,
                                            const float* __restrict__ Wl,
                                            const float* __restrict__ Wr,
                                            short* __restrict__ Bt,
                                            int K, int Kp) {
    short (*Lw)[128] = (short(*)[128])L;
    const int t = threadIdx.x;
    const float* W = (bt < 2) ? Wl : Wr;
    const int ncol0 = (bt & 1) * 128;
    #pragma unroll
    for (int pass = 0; pass < 4; ++pass) {
        int u = pass * 256 + t;               // 1024 elems: k_r = u>>7, n_l = u&127
        int k_r = u >> 7, n_l = u & 127;
        int k = kc * 8 + k_r;
        Lw[k_r][n_l] = (k < K) ? f2bf(W[(size_t)k * 256 + ncol0 + n_l]) : (short)0;
    }
    __syncthreads();
    if (t < 128) {
        bf16x8 v;
        #pragma unroll
        for (int j = 0; j < 8; ++j) v[j] = Lw[j][t];
        *(bf16x8*)(Bt + (size_t)bt * ((size_t)Kp * 128) + (size_t)kc * 1024 + (size_t)t * 8) = v;
    }
}

// ---------------- edge_count (standalone, runs first) ----------------
__global__ __launch_bounds__(256) void edge_count_kernel(const int* __restrict__ ei,
                                                         int* __restrict__ counts) {
    int e = blockIdx.x * 256 + threadIdx.x;
    if (e >= E_TOT) return;
    int dst = (e < N_EDGES) ? ei[N_EDGES + e] : (e - N_EDGES);
    atomicAdd(&counts[dst], 1);
}

// ---------------- CSR scan (single block) ----------------
__global__ __launch_bounds__(1024) void scan_kernel(const int* __restrict__ counts,
                                                    int* __restrict__ offs,
                                                    int* __restrict__ cursor) {
    __shared__ int wsum[16];
    int t = threadIdx.x;
    int lane = t & 63, wv = t >> 6;
    int base = t * 32;
    int local[32];
    int s = 0;
    #pragma unroll
    for (int j = 0; j < 32; ++j) {
        int i = base + j;
        int c = (i < N_NODES) ? counts[i] : 0;
        local[j] = s;
        s += c;
    }
    int incl = s;
    #pragma unroll
    for (int off = 1; off < 64; off <<= 1) {
        int v = __shfl_up(incl, off, 64);
        if (lane >= off) incl += v;
    }
    if (lane == 63) wsum[wv] = incl;
    __syncthreads();
    if (t == 0) {
        int run = 0;
        #pragma unroll
        for (int w2 = 0; w2 < 16; ++w2) { int v = wsum[w2]; wsum[w2] = run; run += v; }
        offs[N_NODES] = run;
    }
    __syncthreads();
    int thrExc = wsum[wv] + incl - s;
    #pragma unroll
    for (int j = 0; j < 32; ++j) {
        int i = base + j;
        if (i < N_NODES) {
            int o = thrExc + local[j];
            offs[i] = o;
            cursor[i] = o;
        }
    }
}

// ---------------- merged prep2: pack_x | pack_w(L1) | pack_w(L2) | scatter ----------------
// scatter hides under the BW-bound pack phase (was merged with GEMM1; that
// co-run is the prime suspect for GEMM1's 100us, so GEMM1 now runs pure).
__global__ __launch_bounds__(256) void prep2_kernel(
    const float* __restrict__ x, short* __restrict__ A,
    const float* __restrict__ Wl1, const float* __restrict__ Wr1, short* __restrict__ Wbf,
    const float* __restrict__ Wl2, const float* __restrict__ Wr2, short* __restrict__ W2bf,
    const int* __restrict__ ei, int* __restrict__ cursor, int* __restrict__ srcs)
{
    __shared__ short L[128 * 72];
    const int b = blockIdx.x;
    if (b < NB_PXS) {
        pack_x_stripe_body(b, L, x, A);
    } else if (b < NB_PXS + NB_PW1) {
        int r = b - NB_PXS;
        pack_w_body(r % (KP1 / 8), r / (KP1 / 8), L, Wl1, Wr1, Wbf, IN_DIM, KP1);
    } else if (b < NB_PXS + NB_PW1 + NB_PW2) {
        int r = b - NB_PXS - NB_PW1;
        pack_w_body(r % (256 / 8), r / (256 / 8), L, Wl2, Wr2, W2bf, 256, 256);
    } else {
        int r = b - NB_PXS - NB_PW1 - NB_PW2;
        int e = r * 256 + threadIdx.x;
        if (e >= E_TOT) return;
        int src, dst;
        if (e < N_EDGES) { src = ei[e]; dst = ei[N_EDGES + e]; }
        else { src = e - N_EDGES; dst = src; }
        int pos = atomicAdd(&cursor[dst], 1);
        srcs[pos] = src;
    }
}

// ---------------- bf16 MFMA GEMM, 128x128 tile (R2-proven body) ----------------
__global__ __launch_bounds__(256) void gemm_bf16_kernel(
    const short* __restrict__ A, const short* __restrict__ B,
    short* __restrict__ C,
    const float* __restrict__ biasLo, const float* __restrict__ biasHi,
    int Mstore, int Kp)
{
    __shared__ short As[4096];   // [4 kc][128 m][8 k]
    __shared__ short Bs[4096];
    const int id = blockIdx.x;
    int bmT, bnT;
    if (id < 928) { int grp = id >> 5, w32 = id & 31; bmT = grp * 8 + (w32 & 7); bnT = w32 >> 3; }
    else          { int r = id - 928;  bmT = 232 + (r >> 2); bnT = r & 3; }
    const int tid  = threadIdx.x;
    const int wave = tid >> 6;
    const int lane = tid & 63;
    const int l15  = lane & 15;
    const int quad = lane >> 4;

    const size_t tstride = (size_t)Kp * 128;
    const short* aPtr = A + (size_t)bmT * tstride + wave * 1024 + lane * 8;
    const short* bPtr = B + (size_t)bnT * tstride + wave * 1024 + lane * 8;
    short* AsW = &As[wave * 1024];
    short* BsW = &Bs[wave * 1024];

    const int wm = (wave & 1) * 64;
    const int wn = (wave >> 1) * 64;

    f32x4 acc[4][4] = {};

    for (int it = 0; it < Kp / 32; ++it) {
        async16(AsW,       aPtr);
        async16(AsW + 512, aPtr + 512);
        async16(BsW,       bPtr);
        async16(BsW + 512, bPtr + 512);
        aPtr += 4096; bPtr += 4096;
        __syncthreads();

        bf16x8 af[4], bfr[4];
        #pragma unroll
        for (int i = 0; i < 4; ++i)
            af[i] = *(const bf16x8*)&As[quad * 1024 + (wm + i * 16 + l15) * 8];
        #pragma unroll
        for (int i = 0; i < 4; ++i)
            bfr[i] = *(const bf16x8*)&Bs[quad * 1024 + (wn + i * 16 + l15) * 8];
        #pragma unroll
        for (int mi = 0; mi < 4; ++mi)
            #pragma unroll
            for (int ni = 0; ni < 4; ++ni)
                acc[mi][ni] = __builtin_amdgcn_mfma_f32_16x16x32_bf16(
                    af[mi], bfr[ni], acc[mi][ni], 0, 0, 0);
        __syncthreads();
    }

    // C/D layout: col = lane&15, row = quad*4 + reg  [measured m89/m91]
    const int bm = bmT * 128, bn = bnT * 128;
    #pragma unroll
    for (int mi = 0; mi < 4; ++mi) {
        int row = bm + wm + mi * 16 + quad * 4;
        #pragma unroll
        for (int ni = 0; ni < 4; ++ni) {
            int col = bn + wn + ni * 16 + l15;
            float bv = (col < 256) ? biasLo[col] : biasHi[col - 256];
            #pragma unroll
            for (int r = 0; r < 4; ++r) {
                int rr = row + r;
                if (rr < Mstore)
                    C[(size_t)rr * 512 + col] = f2bf(acc[mi][ni][r] + bv);
            }
        }
    }
}

// ---------------- layer-1 fused logits+softmax+aggregate ----------------
__global__ __launch_bounds__(256) void fused_aggr1_kernel(
    const int* __restrict__ offs, const int* __restrict__ srcs,
    const short* __restrict__ C, const float* __restrict__ att,
    const float* __restrict__ bias, short* __restrict__ h1b)
{
    int wid = (int)((blockIdx.x * 256 + threadIdx.x) >> 6);
    int lane = threadIdx.x & 63;
    if (wid >= N_NODES) return;
    int n = wid;
    int half = lane >> 5;
    int l5 = lane & 31;
    int d0 = l5 * 8;
    float attv[8], xr[8];
    {
        float4 aa = *(const float4*)(att + d0);
        float4 ab = *(const float4*)(att + d0 + 4);
        attv[0]=aa.x; attv[1]=aa.y; attv[2]=aa.z; attv[3]=aa.w;
        attv[4]=ab.x; attv[5]=ab.y; attv[6]=ab.z; attv[7]=ab.w;
        bf16x8 xv = *(const bf16x8*)(C + (size_t)n * 512 + 256 + d0);
        #pragma unroll
        for (int j = 0; j < 8; ++j) xr[j] = bf2f(xv[j]);
    }
    float a[8] = {};
    float den = 0.f;
    int beg = offs[n], end = offs[n + 1];
    for (int i = beg; i < end; i += 8) {
        bool act[4];
        int ss[4];
        bf16x8 xlv[4];
        #pragma unroll
        for (int u = 0; u < 4; ++u) {
            int idx = i + 2 * u + half;
            act[u] = idx < end;
            ss[u] = srcs[act[u] ? idx : (end - 1)];
        }
        #pragma unroll
        for (int u = 0; u < 4; ++u)
            xlv[u] = *(const bf16x8*)(C + (size_t)ss[u] * 512 + d0);
        #pragma unroll
        for (int u = 0; u < 4; ++u) {
            float xl[8];
            #pragma unroll
            for (int j = 0; j < 8; ++j) xl[j] = bf2f(xlv[u][j]);
            float p = 0.f;
            #pragma unroll
            for (int j = 0; j < 8; ++j) p += lrelu(xl[j] + xr[j]) * attv[j];
            p += __shfl_xor(p, 1, 64);
            p += __shfl_xor(p, 2, 64);
            p += __shfl_xor(p, 4, 64);
            float wgt = act[u] ? __expf(p) : 0.f;
            den += wgt;
            #pragma unroll
            for (int j = 0; j < 8; ++j) a[j] += wgt * xl[j];
        }
    }
    den += __shfl_xor(den, 32, 64);
    #pragma unroll
    for (int j = 0; j < 8; ++j) a[j] += __shfl_xor(a[j], 32, 64);
    if (half == 0) {
        float inv = 1.f / (den + 1e-16f);
        bf16x8 o;
        #pragma unroll
        for (int j = 0; j < 8; ++j) o[j] = f2bf(elu1(a[j] * inv + bias[d0 + j]));
        // A'2 layout: [n>>7][kchunk=l5][n&127][8]
        *(bf16x8*)(h1b + (size_t)(n >> 7) * TS2 + (size_t)l5 * 1024 + (size_t)(n & 127) * 8) = o;
    }
}

// ---------------- layer-2 fused (1 head x 256), f32 output ----------------
__global__ __launch_bounds__(256) void fused_aggr2_kernel(
    const int* __restrict__ offs, const int* __restrict__ srcs,
    const short* __restrict__ C, const float* __restrict__ att,
    const float* __restrict__ bias, float* __restrict__ h2)
{
    int wid = (int)((blockIdx.x * 256 + threadIdx.x) >> 6);
    int lane = threadIdx.x & 63;
    if (wid >= N_NODES) return;
    int n = wid;
    int half = lane >> 5;
    int l5 = lane & 31;
    int d0 = l5 * 8;
    float attv[8], xr[8];
    {
        float4 aa = *(const float4*)(att + d0);
        float4 ab = *(const float4*)(att + d0 + 4);
        attv[0]=aa.x; attv[1]=aa.y; attv[2]=aa.z; attv[3]=aa.w;
        attv[4]=ab.x; attv[5]=ab.y; attv[6]=ab.z; attv[7]=ab.w;
        bf16x8 xv = *(const bf16x8*)(C + (size_t)n * 512 + 256 + d0);
        #pragma unroll
        for (int j = 0; j < 8; ++j) xr[j] = bf2f(xv[j]);
    }
    float a[8] = {};
    float den = 0.f;
    int beg = offs[n], end = offs[n + 1];
    for (int i = beg; i < end; i += 8) {
        bool act[4];
        int ss[4];
        bf16x8 xlv[4];
        #pragma unroll
        for (int u = 0; u < 4; ++u) {
            int idx = i + 2 * u + half;
            act[u] = idx < end;
            ss[u] = srcs[act[u] ? idx : (end - 1)];
        }
        #pragma unroll
        for (int u = 0; u < 4; ++u)
            xlv[u] = *(const bf16x8*)(C + (size_t)ss[u] * 512 + d0);
        #pragma unroll
        for (int u = 0; u < 4; ++u) {
            float xl[8];
            #pragma unroll
            for (int j = 0; j < 8; ++j) xl[j] = bf2f(xlv[u][j]);
            float p = 0.f;
            #pragma unroll
            for (int j = 0; j < 8; ++j) p += lrelu(xl[j] + xr[j]) * attv[j];
            p += __shfl_xor(p, 1, 64);
            p += __shfl_xor(p, 2, 64);
            p += __shfl_xor(p, 4, 64);
            p += __shfl_xor(p, 8, 64);
            p += __shfl_xor(p, 16, 64);
            float wgt = act[u] ? __expf(p) : 0.f;
            den += wgt;
            #pragma unroll
            for (int j = 0; j < 8; ++j) a[j] += wgt * xl[j];
        }
    }
    den += __shfl_xor(den, 32, 64);
    #pragma unroll
    for (int j = 0; j < 8; ++j) a[j] += __shfl_xor(a[j], 32, 64);
    if (half == 0) {
        float inv = 1.f / (den + 1e-16f);
        float4 o0, o1;
        o0.x = elu1(a[0] * inv + bias[d0 + 0]);
        o0.y = elu1(a[1] * inv + bias[d0 + 1]);
        o0.z = elu1(a[2] * inv + bias[d0 + 2]);
        o0.w = elu1(a[3] * inv + bias[d0 + 3]);
        o1.x = elu1(a[4] * inv + bias[d0 + 4]);
        o1.y = elu1(a[5] * inv + bias[d0 + 5]);
        o1.z = elu1(a[6] * inv + bias[d0 + 6]);
        o1.w = elu1(a[7] * inv + bias[d0 + 7]);
        *(float4*)(h2 + (size_t)n * 256 + d0) = o0;
        *(float4*)(h2 + (size_t)n * 256 + d0 + 4) = o1;
    }
}

// ---------------- MLP head: one block (128 thr) per batch row ----------------
__global__ __launch_bounds__(128) void head_mlp_kernel(
    const float* __restrict__ h2, const int* __restrict__ sel,
    const float* __restrict__ wt, const float* __restrict__ mut,
    const float* __restrict__ W1, const float* __restrict__ b1,
    const float* __restrict__ W2, const float* __restrict__ b2,
    const float* __restrict__ W3, const float* __restrict__ b3,
    float* __restrict__ out)
{
    __shared__ float comb[296];
    __shared__ float z1[128];
    int b = blockIdx.x;
    int t = threadIdx.x;
    const float* hrow = h2 + (size_t)sel[b] * 256;
    comb[t] = hrow[t];
    comb[128 + t] = hrow[128 + t];
    if (t < 40) comb[256 + t] = (t < 20) ? wt[b * 20 + t] : mut[b * 20 + t - 20];
    __syncthreads();
    float s = b1[t];
    #pragma unroll 8
    for (int i = 0; i < 296; ++i) s += comb[i] * W1[i * 128 + t];
    z1[t] = fmaxf(s, 0.f);
    __syncthreads();
    if (t < 64) {
        float s2 = b2[t];
        #pragma unroll 8
        for (int i = 0; i < 128; ++i) s2 += z1[i] * W2[i * 64 + t];
        float v = fmaxf(s2, 0.f) * W3[t];
        #pragma unroll
        for (int off = 32; off > 0; off >>= 1) v += __shfl_xor(v, off, 64);
        if (t == 0) out[b] = v + b3[0];
    }
}

// ---------------- launch ----------------
extern "C" void kernel_launch(void* const* d_in, const int* in_sizes, int n_in,
                              void* d_out, int out_size, void* d_ws, size_t ws_size,
                              hipStream_t stream) {
    const float* x     = (const float*)d_in[0];
    const int*   ei    = (const int*)  d_in[1];
    const int*   sel   = (const int*)  d_in[2];
    const float* wt    = (const float*)d_in[3];
    const float* mut   = (const float*)d_in[4];
    const float* Wl1   = (const float*)d_in[5];
    const float* bl1   = (const float*)d_in[6];
    const float* Wr1   = (const float*)d_in[7];
    const float* br1   = (const float*)d_in[8];
    const float* att1  = (const float*)d_in[9];
    const float* bias1 = (const float*)d_in[10];
    const float* Wl2   = (const float*)d_in[11];
    const float* bl2   = (const float*)d_in[12];
    const float* Wr2   = (const float*)d_in[13];
    const float* br2   = (const float*)d_in[14];
    const float* att2  = (const float*)d_in[15];
    const float* bias2 = (const float*)d_in[16];
    const float* hW1   = (const float*)d_in[17];
    const float* hb1   = (const float*)d_in[18];
    const float* hW2   = (const float*)d_in[19];
    const float* hb2   = (const float*)d_in[20];
    const float* hW3   = (const float*)d_in[21];
    const float* hb3   = (const float*)d_in[22];
    float* out = (float*)d_out;

    // workspace layout (256B-aligned chunks)
    char* w = (char*)d_ws;
    size_t off = 0;
    auto alloc = [&](size_t bytes) -> void* {
        void* p = w + off;
        off += (bytes + 255) & ~(size_t)255;
        return p;
    };
    short* Abf    = (short*)alloc((size_t)NBM * TS1 * 2);       // x in A'-tiles; reused as C2 (bf16)
    short* Wbf    = (short*)alloc((size_t)4 * TS1 * 2);         // [Wl1|Wr1] in B'-tiles
    short* C1b    = (short*)alloc((size_t)N_NODES * 512 * 2);   // [xl1|xr1] bf16; reused as h2 f32
    int*   counts = (int*)  alloc((size_t)N_NODES * 4);
    int*   cursor = (int*)  alloc((size_t)N_NODES * 4);
    int*   offs   = (int*)  alloc((size_t)(N_NODES + 1) * 4);
    int*   srcs   = (int*)  alloc((size_t)E_TOT * 4);
    short* H1bf   = (short*)alloc((size_t)NBM * TS2 * 2);       // h1 in A'-tiles (GEMM2 A)
    short* W2bf   = (short*)alloc((size_t)4 * TS2 * 2);         // [Wl2|Wr2] in B'-tiles
    short* C2b = Abf;          // [xl2|xr2] bf16 overlays dead x-tiles
    float* h2  = (float*)C1b;  // h2 f32 overlays dead C1b
    (void)in_sizes; (void)n_in; (void)out_size; (void)ws_size;

    hipMemsetAsync(counts, 0, (size_t)N_NODES * 4, stream);

    // K1: edge_count (CSR histogram)
    edge_count_kernel<<<NB_SC, 256, 0, stream>>>(ei, counts);
    // K2: scan
    scan_kernel<<<1, 1024, 0, stream>>>(counts, offs, cursor);
    // K3: pack_x(stripes) | pack_w(L1) | pack_w(L2) | edge_scatter
    prep2_kernel<<<NB_PREP2, 256, 0, stream>>>(x, Abf, Wl1, Wr1, Wbf, Wl2, Wr2, W2bf,
                                               ei, cursor, srcs);
    // K4: GEMM layer 1 (pure -- attribution experiment)
    gemm_bf16_kernel<<<NB_GEMM, 256, 0, stream>>>(Abf, Wbf, C1b, bl1, br1, N_NODES, KP1);
    // K5: layer-1 aggregate
    fused_aggr1_kernel<<<(N_NODES + 3) / 4, 256, 0, stream>>>(offs, srcs, C1b, att1, bias1, H1bf);
    // K6: GEMM layer 2
    gemm_bf16_kernel<<<NB_GEMM, 256, 0, stream>>>(H1bf, W2bf, C2b, bl2, br2, N_NODES, 256);
    // K7: layer-2 aggregate
    fused_aggr2_kernel<<<(N_NODES + 3) / 4, 256, 0, stream>>>(offs, srcs, C2b, att2, bias2, h2);
    // K8: head
    head_mlp_kernel<<<BQ, 128, 0, stream>>>(h2, sel, wt, mut, hW1, hb1, hW2, hb2, hW3, hb3, out);
}

// Round 5
// 572.419 us; speedup vs baseline: 1.0506x; 1.0506x over previous
//
#include <hip/hip_runtime.h>

// ---------------- problem constants ----------------
#define N_NODES 30000
#define N_EDGES 480000
#define E_TOT   510000        // edges + self loops
#define BQ      4096
#define IN_DIM  1281
#define KP1     1344          // 1281 padded to mult of 64 (pack tile) & 32 (gemm)
#define NKG     (KP1/64)      // 21 col-groups in pack_x
#define MP      30080         // 30000 padded to mult of 128
#define NBM     235           // MP/128
#define TS1     (KP1*128)     // A'/B' tile stride (shorts), layer 1
#define TS2     (256*128)     // tile stride, layer 2

// merged-grid block counts
#define NB_PX   (NBM*NKG)         // 4935 pack_x blocks
#define NB_PW1  ((KP1/8)*4)       // 672 pack_w layer-1 blocks
#define NB_PW2  ((256/8)*4)       // 128 pack_w layer-2 blocks
#define NB_CNT  ((E_TOT+255)/256) // 1993 edge_count / scatter blocks
#define NB_PREP (NB_PX+NB_PW1+NB_PW2+NB_CNT)
#define NB_GEMM 940               // NBM*4 tiles (128x128)

typedef __attribute__((ext_vector_type(8))) short bf16x8;
typedef __attribute__((ext_vector_type(4))) float f32x4;

__device__ __forceinline__ short f2bf(float f) {
    unsigned int u = __builtin_bit_cast(unsigned int, f);
    u += 0x7fffu + ((u >> 16) & 1u);       // RNE
    return (short)(u >> 16);
}

__device__ __forceinline__ float bf2f(short s) {
    unsigned int u = ((unsigned int)(unsigned short)s) << 16;
    return __builtin_bit_cast(float, u);
}

__device__ __forceinline__ void async16(void* lds, const void* g) {
    __builtin_amdgcn_global_load_lds(
        (const __attribute__((address_space(1))) void*)g,
        (__attribute__((address_space(3))) void*)lds, 16, 0, 0);
}

__device__ __forceinline__ float elu1(float x) {
    return x > 0.f ? x : __expf(x) - 1.f;
}

__device__ __forceinline__ float lrelu(float x) {
    return x > 0.f ? x : 0.2f * x;
}

// ---------------- pack bodies (device functions) ----------------
// x (30000x1281 f32) -> A' tile-major: A'[mt][kchunk][m&127][k&7] bf16.
// 32 loads hoisted (full-wave MLP). R5: caller orders blocks slab-major
// (consecutive blocks share one 128-row slab) for DRAM-page locality.
__device__ __forceinline__ void pack_x_body(int mt, int kg, short* L /*[128][72]*/,
                                            const float* __restrict__ x,
                                            short* __restrict__ A) {
    short (*Lx)[72] = (short(*)[72])L;
    const int t = threadIdx.x;
    const int wave = t >> 6, lane = t & 63;
    const int m0 = mt * 128;
    const int col = kg * 64 + lane;
    const bool cok = col < IN_DIM;
    const float* xcol = x + col;
    float v[32];
    #pragma unroll
    for (int j = 0; j < 32; ++j) {
        int ml = j * 4 + wave;
        int m = m0 + ml;
        v[j] = (cok && m < N_NODES) ? xcol[(size_t)m * IN_DIM] : 0.f;
    }
    #pragma unroll
    for (int j = 0; j < 32; ++j) {
        int ml = j * 4 + wave;
        Lx[ml][lane] = f2bf(v[j]);
    }
    __syncthreads();
    short* Atile = A + (size_t)mt * TS1 + (size_t)kg * 8 * 1024;
    #pragma unroll
    for (int pass = 0; pass < 4; ++pass) {
        int u = pass * 256 + t;          // 0..1023
        int tc = u >> 7, ml = u & 127;   // tc 0..7 (this block's 8 kchunks)
        *(bf16x8*)(Atile + (size_t)tc * 1024 + ml * 8) = *(const bf16x8*)&Lx[ml][tc * 8];
    }
}

// W (K x 256 row-major, Wl|Wr) -> B'[bt][kchunk][n&127][k&7]; k-pad zeroed.
__device__ __forceinline__ void pack_w_body(int kc, int bt, short* L /*[8][128]*/,
                                            const float* __restrict__ Wl,
                                            const float* __restrict__ Wr,
                                            short* __restrict__ Bt,
                                            int K, int Kp) {
    short (*Lw)[128] = (short(*)[128])L;
    const int t = threadIdx.x;
    const float* W = (bt < 2) ? Wl : Wr;
    const int ncol0 = (bt & 1) * 128;
    #pragma unroll
    for (int pass = 0; pass < 4; ++pass) {
        int u = pass * 256 + t;               // 1024 elems: k_r = u>>7, n_l = u&127
        int k_r = u >> 7, n_l = u & 127;
        int k = kc * 8 + k_r;
        Lw[k_r][n_l] = (k < K) ? f2bf(W[(size_t)k * 256 + ncol0 + n_l]) : (short)0;
    }
    __syncthreads();
    if (t < 128) {
        bf16x8 v;
        #pragma unroll
        for (int j = 0; j < 8; ++j) v[j] = Lw[j][t];
        *(bf16x8*)(Bt + (size_t)bt * ((size_t)Kp * 128) + (size_t)kc * 1024 + (size_t)t * 8) = v;
    }
}

// ---------------- merged prep: pack_x | pack_w(L1) | pack_w(L2) | edge_count ----------------
__global__ __launch_bounds__(256) void prep_kernel(
    const float* __restrict__ x, short* __restrict__ A,
    const float* __restrict__ Wl1, const float* __restrict__ Wr1, short* __restrict__ Wbf,
    const float* __restrict__ Wl2, const float* __restrict__ Wr2, short* __restrict__ W2bf,
    const int* __restrict__ ei, int* __restrict__ counts)
{
    __shared__ short L[128 * 72];
    const int b = blockIdx.x;
    if (b < NB_PX) {
        pack_x_body(b / NKG, b % NKG, L, x, A);   // slab-major order
    } else if (b < NB_PX + NB_PW1) {
        int r = b - NB_PX;
        pack_w_body(r % (KP1 / 8), r / (KP1 / 8), L, Wl1, Wr1, Wbf, IN_DIM, KP1);
    } else if (b < NB_PX + NB_PW1 + NB_PW2) {
        int r = b - NB_PX - NB_PW1;
        pack_w_body(r % (256 / 8), r / (256 / 8), L, Wl2, Wr2, W2bf, 256, 256);
    } else {
        int r = b - NB_PX - NB_PW1 - NB_PW2;
        int e = r * 256 + threadIdx.x;
        if (e < E_TOT) {
            int dst = (e < N_EDGES) ? ei[N_EDGES + e] : (e - N_EDGES);
            atomicAdd(&counts[dst], 1);
        }
    }
}

// ---------------- bf16 MFMA GEMM, 128x128 tile, double-buffered LDS ----------------
// R5: prefetch tile t+1 into buf^1 BEFORE computing tile t, then ONE
// __syncthreads per iter. The sync's vmcnt(0) drain now only pays the
// latency residual (loads issued ~300 cycles earlier under ds_read+MFMA),
// and the barrier count halves. Same barrier WAR-protects buf (all ds_reads
// complete before any wave overwrites it next iteration).
__device__ __forceinline__ void gemm_body(
    int id,
    const short* __restrict__ A, const short* __restrict__ B,
    short* __restrict__ C,
    const float* __restrict__ biasLo, const float* __restrict__ biasHi,
    int Mstore, int Kp)
{
    __shared__ short As[2][4096];   // [buf][4 kc][128 m][8 k]
    __shared__ short Bs[2][4096];
    int bmT, bnT;
    if (id < 928) { int grp = id >> 5, w32 = id & 31; bmT = grp * 8 + (w32 & 7); bnT = w32 >> 3; }
    else          { int r = id - 928;  bmT = 232 + (r >> 2); bnT = r & 3; }
    const int tid  = threadIdx.x;
    const int wave = tid >> 6;
    const int lane = tid & 63;
    const int l15  = lane & 15;
    const int quad = lane >> 4;

    const size_t tstride = (size_t)Kp * 128;
    const short* aPtr = A + (size_t)bmT * tstride + wave * 1024 + lane * 8;
    const short* bPtr = B + (size_t)bnT * tstride + wave * 1024 + lane * 8;

    const int wm = (wave & 1) * 64;
    const int wn = (wave >> 1) * 64;

    f32x4 acc[4][4] = {};
    const int nt = Kp / 32;

    // prologue: stage tile 0 into buffer 0 (full latency exposed once)
    async16(&As[0][wave * 1024],       aPtr);
    async16(&As[0][wave * 1024 + 512], aPtr + 512);
    async16(&Bs[0][wave * 1024],       bPtr);
    async16(&Bs[0][wave * 1024 + 512], bPtr + 512);
    aPtr += 4096; bPtr += 4096;
    __syncthreads();

    for (int it = 0; it < nt; ++it) {
        const int cur = it & 1, nxt = cur ^ 1;
        if (it + 1 < nt) {
            async16(&As[nxt][wave * 1024],       aPtr);
            async16(&As[nxt][wave * 1024 + 512], aPtr + 512);
            async16(&Bs[nxt][wave * 1024],       bPtr);
            async16(&Bs[nxt][wave * 1024 + 512], bPtr + 512);
            aPtr += 4096; bPtr += 4096;
        }
        bf16x8 af[4], bfr[4];
        #pragma unroll
        for (int i = 0; i < 4; ++i)
            af[i] = *(const bf16x8*)&As[cur][quad * 1024 + (wm + i * 16 + l15) * 8];
        #pragma unroll
        for (int i = 0; i < 4; ++i)
            bfr[i] = *(const bf16x8*)&Bs[cur][quad * 1024 + (wn + i * 16 + l15) * 8];
        #pragma unroll
        for (int mi = 0; mi < 4; ++mi)
            #pragma unroll
            for (int ni = 0; ni < 4; ++ni)
                acc[mi][ni] = __builtin_amdgcn_mfma_f32_16x16x32_bf16(
                    af[mi], bfr[ni], acc[mi][ni], 0, 0, 0);
        __syncthreads();   // drains prefetch (mostly landed) + WAR-protects cur
    }

    // C/D layout: col = lane&15, row = quad*4 + reg  [measured m89/m91]
    const int bm = bmT * 128, bn = bnT * 128;
    #pragma unroll
    for (int mi = 0; mi < 4; ++mi) {
        int row = bm + wm + mi * 16 + quad * 4;
        #pragma unroll
        for (int ni = 0; ni < 4; ++ni) {
            int col = bn + wn + ni * 16 + l15;
            float bv = (col < 256) ? biasLo[col] : biasHi[col - 256];
            #pragma unroll
            for (int r = 0; r < 4; ++r) {
                int rr = row + r;
                if (rr < Mstore)
                    C[(size_t)rr * 512 + col] = f2bf(acc[mi][ni][r] + bv);
            }
        }
    }
}

// standalone GEMM (layer 2)
__global__ __launch_bounds__(256) void gemm_bf16_kernel(
    const short* __restrict__ A, const short* __restrict__ B,
    short* __restrict__ C,
    const float* __restrict__ biasLo, const float* __restrict__ biasHi,
    int Mstore, int Kp)
{
    gemm_body(blockIdx.x, A, B, C, biasLo, biasHi, Mstore, Kp);
}

// merged: GEMM layer 1 blocks [0,940) + edge_scatter blocks [940, 940+NB_CNT)
__global__ __launch_bounds__(256) void gemm1_scatter_kernel(
    const short* __restrict__ A, const short* __restrict__ B,
    short* __restrict__ C,
    const float* __restrict__ biasLo, const float* __restrict__ biasHi,
    const int* __restrict__ ei, int* __restrict__ cursor, int* __restrict__ srcs)
{
    const int b = blockIdx.x;
    if (b < NB_GEMM) {
        gemm_body(b, A, B, C, biasLo, biasHi, N_NODES, KP1);
    } else {
        int e = (b - NB_GEMM) * 256 + threadIdx.x;
        if (e >= E_TOT) return;
        int src, dst;
        if (e < N_EDGES) { src = ei[e]; dst = ei[N_EDGES + e]; }
        else { src = e - N_EDGES; dst = src; }
        int pos = atomicAdd(&cursor[dst], 1);
        srcs[pos] = src;
    }
}

// ---------------- CSR scan (single block) ----------------
__global__ __launch_bounds__(1024) void scan_kernel(const int* __restrict__ counts,
                                                    int* __restrict__ offs,
                                                    int* __restrict__ cursor) {
    __shared__ int wsum[16];
    int t = threadIdx.x;
    int lane = t & 63, wv = t >> 6;
    int base = t * 32;
    int local[32];
    int s = 0;
    #pragma unroll
    for (int j = 0; j < 32; ++j) {
        int i = base + j;
        int c = (i < N_NODES) ? counts[i] : 0;
        local[j] = s;
        s += c;
    }
    int incl = s;
    #pragma unroll
    for (int off = 1; off < 64; off <<= 1) {
        int v = __shfl_up(incl, off, 64);
        if (lane >= off) incl += v;
    }
    if (lane == 63) wsum[wv] = incl;
    __syncthreads();
    if (t == 0) {
        int run = 0;
        #pragma unroll
        for (int w2 = 0; w2 < 16; ++w2) { int v = wsum[w2]; wsum[w2] = run; run += v; }
        offs[N_NODES] = run;
    }
    __syncthreads();
    int thrExc = wsum[wv] + incl - s;
    #pragma unroll
    for (int j = 0; j < 32; ++j) {
        int i = base + j;
        if (i < N_NODES) {
            int o = thrExc + local[j];
            offs[i] = o;
            cursor[i] = o;
        }
    }
}

// ---------------- layer-1 fused logits+softmax+aggregate ----------------
__global__ __launch_bounds__(256) void fused_aggr1_kernel(
    const int* __restrict__ offs, const int* __restrict__ srcs,
    const short* __restrict__ C, const float* __restrict__ att,
    const float* __restrict__ bias, short* __restrict__ h1b)
{
    int wid = (int)((blockIdx.x * 256 + threadIdx.x) >> 6);
    int lane = threadIdx.x & 63;
    if (wid >= N_NODES) return;
    int n = wid;
    int half = lane >> 5;
    int l5 = lane & 31;
    int d0 = l5 * 8;
    float attv[8], xr[8];
    {
        float4 aa = *(const float4*)(att + d0);
        float4 ab = *(const float4*)(att + d0 + 4);
        attv[0]=aa.x; attv[1]=aa.y; attv[2]=aa.z; attv[3]=aa.w;
        attv[4]=ab.x; attv[5]=ab.y; attv[6]=ab.z; attv[7]=ab.w;
        bf16x8 xv = *(const bf16x8*)(C + (size_t)n * 512 + 256 + d0);
        #pragma unroll
        for (int j = 0; j < 8; ++j) xr[j] = bf2f(xv[j]);
    }
    float a[8] = {};
    float den = 0.f;
    int beg = offs[n], end = offs[n + 1];
    for (int i = beg; i < end; i += 8) {
        bool act[4];
        int ss[4];
        bf16x8 xlv[4];
        #pragma unroll
        for (int u = 0; u < 4; ++u) {
            int idx = i + 2 * u + half;
            act[u] = idx < end;
            ss[u] = srcs[act[u] ? idx : (end - 1)];
        }
        #pragma unroll
        for (int u = 0; u < 4; ++u)
            xlv[u] = *(const bf16x8*)(C + (size_t)ss[u] * 512 + d0);
        #pragma unroll
        for (int u = 0; u < 4; ++u) {
            float xl[8];
            #pragma unroll
            for (int j = 0; j < 8; ++j) xl[j] = bf2f(xlv[u][j]);
            float p = 0.f;
            #pragma unroll
            for (int j = 0; j < 8; ++j) p += lrelu(xl[j] + xr[j]) * attv[j];
            p += __shfl_xor(p, 1, 64);
            p += __shfl_xor(p, 2, 64);
            p += __shfl_xor(p, 4, 64);
            float wgt = act[u] ? __expf(p) : 0.f;
            den += wgt;
            #pragma unroll
            for (int j = 0; j < 8; ++j) a[j] += wgt * xl[j];
        }
    }
    den += __shfl_xor(den, 32, 64);
    #pragma unroll
    for (int j = 0; j < 8; ++j) a[j] += __shfl_xor(a[j], 32, 64);
    if (half == 0) {
        float inv = 1.f / (den + 1e-16f);
        bf16x8 o;
        #pragma unroll
        for (int j = 0; j < 8; ++j) o[j] = f2bf(elu1(a[j] * inv + bias[d0 + j]));
        // A'2 layout: [n>>7][kchunk=l5][n&127][8]
        *(bf16x8*)(h1b + (size_t)(n >> 7) * TS2 + (size_t)l5 * 1024 + (size_t)(n & 127) * 8) = o;
    }
}

// ---------------- layer-2 fused (1 head x 256), f32 output ----------------
__global__ __launch_bounds__(256) void fused_aggr2_kernel(
    const int* __restrict__ offs, const int* __restrict__ srcs,
    const short* __restrict__ C, const float* __restrict__ att,
    const float* __restrict__ bias, float* __restrict__ h2)
{
    int wid = (int)((blockIdx.x * 256 + threadIdx.x) >> 6);
    int lane = threadIdx.x & 63;
    if (wid >= N_NODES) return;
    int n = wid;
    int half = lane >> 5;
    int l5 = lane & 31;
    int d0 = l5 * 8;
    float attv[8], xr[8];
    {
        float4 aa = *(const float4*)(att + d0);
        float4 ab = *(const float4*)(att + d0 + 4);
        attv[0]=aa.x; attv[1]=aa.y; attv[2]=aa.z; attv[3]=aa.w;
        attv[4]=ab.x; attv[5]=ab.y; attv[6]=ab.z; attv[7]=ab.w;
        bf16x8 xv = *(const bf16x8*)(C + (size_t)n * 512 + 256 + d0);
        #pragma unroll
        for (int j = 0; j < 8; ++j) xr[j] = bf2f(xv[j]);
    }
    float a[8] = {};
    float den = 0.f;
    int beg = offs[n], end = offs[n + 1];
    for (int i = beg; i < end; i += 8) {
        bool act[4];
        int ss[4];
        bf16x8 xlv[4];
        #pragma unroll
        for (int u = 0; u < 4; ++u) {
            int idx = i + 2 * u + half;
            act[u] = idx < end;
            ss[u] = srcs[act[u] ? idx : (end - 1)];
        }
        #pragma unroll
        for (int u = 0; u < 4; ++u)
            xlv[u] = *(const bf16x8*)(C + (size_t)ss[u] * 512 + d0);
        #pragma unroll
        for (int u = 0; u < 4; ++u) {
            float xl[8];
            #pragma unroll
            for (int j = 0; j < 8; ++j) xl[j] = bf2f(xlv[u][j]);
            float p = 0.f;
            #pragma unroll
            for (int j = 0; j < 8; ++j) p += lrelu(xl[j] + xr[j]) * attv[j];
            p += __shfl_xor(p, 1, 64);
            p += __shfl_xor(p, 2, 64);
            p += __shfl_xor(p, 4, 64);
            p += __shfl_xor(p, 8, 64);
            p += __shfl_xor(p, 16, 64);
            float wgt = act[u] ? __expf(p) : 0.f;
            den += wgt;
            #pragma unroll
            for (int j = 0; j < 8; ++j) a[j] += wgt * xl[j];
        }
    }
    den += __shfl_xor(den, 32, 64);
    #pragma unroll
    for (int j = 0; j < 8; ++j) a[j] += __shfl_xor(a[j], 32, 64);
    if (half == 0) {
        float inv = 1.f / (den + 1e-16f);
        float4 o0, o1;
        o0.x = elu1(a[0] * inv + bias[d0 + 0]);
        o0.y = elu1(a[1] * inv + bias[d0 + 1]);
        o0.z = elu1(a[2] * inv + bias[d0 + 2]);
        o0.w = elu1(a[3] * inv + bias[d0 + 3]);
        o1.x = elu1(a[4] * inv + bias[d0 + 4]);
        o1.y = elu1(a[5] * inv + bias[d0 + 5]);
        o1.z = elu1(a[6] * inv + bias[d0 + 6]);
        o1.w = elu1(a[7] * inv + bias[d0 + 7]);
        *(float4*)(h2 + (size_t)n * 256 + d0) = o0;
        *(float4*)(h2 + (size_t)n * 256 + d0 + 4) = o1;
    }
}

// ---------------- MLP head: one block (128 thr) per batch row ----------------
__global__ __launch_bounds__(128) void head_mlp_kernel(
    const float* __restrict__ h2, const int* __restrict__ sel,
    const float* __restrict__ wt, const float* __restrict__ mut,
    const float* __restrict__ W1, const float* __restrict__ b1,
    const float* __restrict__ W2, const float* __restrict__ b2,
    const float* __restrict__ W3, const float* __restrict__ b3,
    float* __restrict__ out)
{
    __shared__ float comb[296];
    __shared__ float z1[128];
    int b = blockIdx.x;
    int t = threadIdx.x;
    const float* hrow = h2 + (size_t)sel[b] * 256;
    comb[t] = hrow[t];
    comb[128 + t] = hrow[128 + t];
    if (t < 40) comb[256 + t] = (t < 20) ? wt[b * 20 + t] : mut[b * 20 + t - 20];
    __syncthreads();
    float s = b1[t];
    #pragma unroll 8
    for (int i = 0; i < 296; ++i) s += comb[i] * W1[i * 128 + t];
    z1[t] = fmaxf(s, 0.f);
    __syncthreads();
    if (t < 64) {
        float s2 = b2[t];
        #pragma unroll 8
        for (int i = 0; i < 128; ++i) s2 += z1[i] * W2[i * 64 + t];
        float v = fmaxf(s2, 0.f) * W3[t];
        #pragma unroll
        for (int off = 32; off > 0; off >>= 1) v += __shfl_xor(v, off, 64);
        if (t == 0) out[b] = v + b3[0];
    }
}

// ---------------- launch ----------------
extern "C" void kernel_launch(void* const* d_in, const int* in_sizes, int n_in,
                              void* d_out, int out_size, void* d_ws, size_t ws_size,
                              hipStream_t stream) {
    const float* x     = (const float*)d_in[0];
    const int*   ei    = (const int*)  d_in[1];
    const int*   sel   = (const int*)  d_in[2];
    const float* wt    = (const float*)d_in[3];
    const float* mut   = (const float*)d_in[4];
    const float* Wl1   = (const float*)d_in[5];
    const float* bl1   = (const float*)d_in[6];
    const float* Wr1   = (const float*)d_in[7];
    const float* br1   = (const float*)d_in[8];
    const float* att1  = (const float*)d_in[9];
    const float* bias1 = (const float*)d_in[10];
    const float* Wl2   = (const float*)d_in[11];
    const float* bl2   = (const float*)d_in[12];
    const float* Wr2   = (const float*)d_in[13];
    const float* br2   = (const float*)d_in[14];
    const float* att2  = (const float*)d_in[15];
    const float* bias2 = (const float*)d_in[16];
    const float* hW1   = (const float*)d_in[17];
    const float* hb1   = (const float*)d_in[18];
    const float* hW2   = (const float*)d_in[19];
    const float* hb2   = (const float*)d_in[20];
    const float* hW3   = (const float*)d_in[21];
    const float* hb3   = (const float*)d_in[22];
    float* out = (float*)d_out;

    // workspace layout (256B-aligned chunks)
    char* w = (char*)d_ws;
    size_t off = 0;
    auto alloc = [&](size_t bytes) -> void* {
        void* p = w + off;
        off += (bytes + 255) & ~(size_t)255;
        return p;
    };
    short* Abf    = (short*)alloc((size_t)NBM * TS1 * 2);       // x in A'-tiles; reused as C2 (bf16)
    short* Wbf    = (short*)alloc((size_t)4 * TS1 * 2);         // [Wl1|Wr1] in B'-tiles
    short* C1b    = (short*)alloc((size_t)N_NODES * 512 * 2);   // [xl1|xr1] bf16; reused as h2 f32
    int*   counts = (int*)  alloc((size_t)N_NODES * 4);
    int*   cursor = (int*)  alloc((size_t)N_NODES * 4);
    int*   offs   = (int*)  alloc((size_t)(N_NODES + 1) * 4);
    int*   srcs   = (int*)  alloc((size_t)E_TOT * 4);
    short* H1bf   = (short*)alloc((size_t)NBM * TS2 * 2);       // h1 in A'-tiles (GEMM2 A)
    short* W2bf   = (short*)alloc((size_t)4 * TS2 * 2);         // [Wl2|Wr2] in B'-tiles
    short* C2b = Abf;          // [xl2|xr2] bf16 overlays dead x-tiles
    float* h2  = (float*)C1b;  // h2 f32 overlays dead C1b
    (void)in_sizes; (void)n_in; (void)out_size; (void)ws_size;

    hipMemsetAsync(counts, 0, (size_t)N_NODES * 4, stream);

    // K1: pack_x | pack_w(L1) | pack_w(L2) | edge_count
    prep_kernel<<<NB_PREP, 256, 0, stream>>>(x, Abf, Wl1, Wr1, Wbf, Wl2, Wr2, W2bf, ei, counts);
    // K2: scan
    scan_kernel<<<1, 1024, 0, stream>>>(counts, offs, cursor);
    // K3: GEMM layer 1 (double-buffered) | edge_scatter
    gemm1_scatter_kernel<<<NB_GEMM + NB_CNT, 256, 0, stream>>>(
        Abf, Wbf, C1b, bl1, br1, ei, cursor, srcs);
    // K4: layer-1 aggregate
    fused_aggr1_kernel<<<(N_NODES + 3) / 4, 256, 0, stream>>>(offs, srcs, C1b, att1, bias1, H1bf);
    // K5: GEMM layer 2 (double-buffered)
    gemm_bf16_kernel<<<NB_GEMM, 256, 0, stream>>>(H1bf, W2bf, C2b, bl2, br2, N_NODES, 256);
    // K6: layer-2 aggregate
    fused_aggr2_kernel<<<(N_NODES + 3) / 4, 256, 0, stream>>>(offs, srcs, C2b, att2, bias2, h2);
    // K7: head
    head_mlp_kernel<<<BQ, 128, 0, stream>>>(h2, sel, wt, mut, hW1, hb1, hW2, hb2, hW3, hb3, out);
}

// Round 6
// 537.686 us; speedup vs baseline: 1.1184x; 1.0646x over previous
//
#include <hip/hip_runtime.h>

// ---------------- problem constants ----------------
#define N_NODES 30000
#define N_EDGES 480000
#define E_TOT   510000        // edges + self loops
#define BQ      4096
#define IN_DIM  1281
#define KP1     1344          // 1281 padded to mult of 64 (pack tile) & 32 (gemm)
#define NKG     (KP1/64)      // 21 col-groups in pack_x
#define MP      30080         // 30000 padded to mult of 128
#define NBM     235           // MP/128
#define TS1     (KP1*128)     // A'/B' tile stride (shorts), layer 1
#define TS2     (256*128)     // tile stride, layer 2

// merged-grid block counts
#define NB_PX   (NBM*NKG)         // 4935 pack_x blocks
#define NB_PW1  ((KP1/8)*4)       // 672 pack_w layer-1 blocks
#define NB_PW2  ((256/8)*4)       // 128 pack_w layer-2 blocks
#define NB_CNT  ((E_TOT+255)/256) // 1993 edge_count / scatter blocks
#define NB_PREP (NB_PX+NB_PW1+NB_PW2+NB_CNT)
#define NB_GEMM 940               // NBM*4 tiles (128x128)

typedef __attribute__((ext_vector_type(8))) short bf16x8;
typedef __attribute__((ext_vector_type(4))) float f32x4;

__device__ __forceinline__ short f2bf(float f) {
    unsigned int u = __builtin_bit_cast(unsigned int, f);
    u += 0x7fffu + ((u >> 16) & 1u);       // RNE
    return (short)(u >> 16);
}

__device__ __forceinline__ float bf2f(short s) {
    unsigned int u = ((unsigned int)(unsigned short)s) << 16;
    return __builtin_bit_cast(float, u);
}

__device__ __forceinline__ void async16(void* lds, const void* g) {
    __builtin_amdgcn_global_load_lds(
        (const __attribute__((address_space(1))) void*)g,
        (__attribute__((address_space(3))) void*)lds, 16, 0, 0);
}

__device__ __forceinline__ float elu1(float x) {
    return x > 0.f ? x : __expf(x) - 1.f;
}

__device__ __forceinline__ float lrelu(float x) {
    return x > 0.f ? x : 0.2f * x;
}

// ---------------- pack bodies (device functions) ----------------
// x (30000x1281 f32) -> A' tile-major: A'[mt][kchunk][m&127][k&7] bf16.
// 32 loads hoisted (full-wave MLP); caller orders blocks slab-major.
__device__ __forceinline__ void pack_x_body(int mt, int kg, short* L /*[128][72]*/,
                                            const float* __restrict__ x,
                                            short* __restrict__ A) {
    short (*Lx)[72] = (short(*)[72])L;
    const int t = threadIdx.x;
    const int wave = t >> 6, lane = t & 63;
    const int m0 = mt * 128;
    const int col = kg * 64 + lane;
    const bool cok = col < IN_DIM;
    const float* xcol = x + col;
    float v[32];
    #pragma unroll
    for (int j = 0; j < 32; ++j) {
        int ml = j * 4 + wave;
        int m = m0 + ml;
        v[j] = (cok && m < N_NODES) ? xcol[(size_t)m * IN_DIM] : 0.f;
    }
    #pragma unroll
    for (int j = 0; j < 32; ++j) {
        int ml = j * 4 + wave;
        Lx[ml][lane] = f2bf(v[j]);
    }
    __syncthreads();
    short* Atile = A + (size_t)mt * TS1 + (size_t)kg * 8 * 1024;
    #pragma unroll
    for (int pass = 0; pass < 4; ++pass) {
        int u = pass * 256 + t;          // 0..1023
        int tc = u >> 7, ml = u & 127;   // tc 0..7 (this block's 8 kchunks)
        *(bf16x8*)(Atile + (size_t)tc * 1024 + ml * 8) = *(const bf16x8*)&Lx[ml][tc * 8];
    }
}

// W (K x 256 row-major, Wl|Wr) -> B'[bt][kchunk][n&127][k&7]; k-pad zeroed.
__device__ __forceinline__ void pack_w_body(int kc, int bt, short* L /*[8][128]*/,
                                            const float* __restrict__ Wl,
                                            const float* __restrict__ Wr,
                                            short* __restrict__ Bt,
                                            int K, int Kp) {
    short (*Lw)[128] = (short(*)[128])L;
    const int t = threadIdx.x;
    const float* W = (bt < 2) ? Wl : Wr;
    const int ncol0 = (bt & 1) * 128;
    #pragma unroll
    for (int pass = 0; pass < 4; ++pass) {
        int u = pass * 256 + t;               // 1024 elems: k_r = u>>7, n_l = u&127
        int k_r = u >> 7, n_l = u & 127;
        int k = kc * 8 + k_r;
        Lw[k_r][n_l] = (k < K) ? f2bf(W[(size_t)k * 256 + ncol0 + n_l]) : (short)0;
    }
    __syncthreads();
    if (t < 128) {
        bf16x8 v;
        #pragma unroll
        for (int j = 0; j < 8; ++j) v[j] = Lw[j][t];
        *(bf16x8*)(Bt + (size_t)bt * ((size_t)Kp * 128) + (size_t)kc * 1024 + (size_t)t * 8) = v;
    }
}

// ---------------- merged prep: pack_x | pack_w(L1) | pack_w(L2) | edge_count ----------------
__global__ __launch_bounds__(256) void prep_kernel(
    const float* __restrict__ x, short* __restrict__ A,
    const float* __restrict__ Wl1, const float* __restrict__ Wr1, short* __restrict__ Wbf,
    const float* __restrict__ Wl2, const float* __restrict__ Wr2, short* __restrict__ W2bf,
    const int* __restrict__ ei, int* __restrict__ counts)
{
    __shared__ short L[128 * 72];
    const int b = blockIdx.x;
    if (b < NB_PX) {
        pack_x_body(b / NKG, b % NKG, L, x, A);   // slab-major order
    } else if (b < NB_PX + NB_PW1) {
        int r = b - NB_PX;
        pack_w_body(r % (KP1 / 8), r / (KP1 / 8), L, Wl1, Wr1, Wbf, IN_DIM, KP1);
    } else if (b < NB_PX + NB_PW1 + NB_PW2) {
        int r = b - NB_PX - NB_PW1;
        pack_w_body(r % (256 / 8), r / (256 / 8), L, Wl2, Wr2, W2bf, 256, 256);
    } else {
        int r = b - NB_PX - NB_PW1 - NB_PW2;
        int e = r * 256 + threadIdx.x;
        if (e < E_TOT) {
            int dst = (e < N_EDGES) ? ei[N_EDGES + e] : (e - N_EDGES);
            atomicAdd(&counts[dst], 1);
        }
    }
}

// ---------------- bf16 MFMA GEMM, 128x128 tile, double-buffered LDS ----------------
__device__ __forceinline__ void gemm_body(
    int id,
    const short* __restrict__ A, const short* __restrict__ B,
    short* __restrict__ C,
    const float* __restrict__ biasLo, const float* __restrict__ biasHi,
    int Mstore, int Kp)
{
    __shared__ short As[2][4096];   // [buf][4 kc][128 m][8 k]
    __shared__ short Bs[2][4096];
    int bmT, bnT;
    if (id < 928) { int grp = id >> 5, w32 = id & 31; bmT = grp * 8 + (w32 & 7); bnT = w32 >> 3; }
    else          { int r = id - 928;  bmT = 232 + (r >> 2); bnT = r & 3; }
    const int tid  = threadIdx.x;
    const int wave = tid >> 6;
    const int lane = tid & 63;
    const int l15  = lane & 15;
    const int quad = lane >> 4;

    const size_t tstride = (size_t)Kp * 128;
    const short* aPtr = A + (size_t)bmT * tstride + wave * 1024 + lane * 8;
    const short* bPtr = B + (size_t)bnT * tstride + wave * 1024 + lane * 8;

    const int wm = (wave & 1) * 64;
    const int wn = (wave >> 1) * 64;

    f32x4 acc[4][4] = {};
    const int nt = Kp / 32;

    // prologue: stage tile 0 into buffer 0
    async16(&As[0][wave * 1024],       aPtr);
    async16(&As[0][wave * 1024 + 512], aPtr + 512);
    async16(&Bs[0][wave * 1024],       bPtr);
    async16(&Bs[0][wave * 1024 + 512], bPtr + 512);
    aPtr += 4096; bPtr += 4096;
    __syncthreads();

    for (int it = 0; it < nt; ++it) {
        const int cur = it & 1, nxt = cur ^ 1;
        if (it + 1 < nt) {
            async16(&As[nxt][wave * 1024],       aPtr);
            async16(&As[nxt][wave * 1024 + 512], aPtr + 512);
            async16(&Bs[nxt][wave * 1024],       bPtr);
            async16(&Bs[nxt][wave * 1024 + 512], bPtr + 512);
            aPtr += 4096; bPtr += 4096;
        }
        bf16x8 af[4], bfr[4];
        #pragma unroll
        for (int i = 0; i < 4; ++i)
            af[i] = *(const bf16x8*)&As[cur][quad * 1024 + (wm + i * 16 + l15) * 8];
        #pragma unroll
        for (int i = 0; i < 4; ++i)
            bfr[i] = *(const bf16x8*)&Bs[cur][quad * 1024 + (wn + i * 16 + l15) * 8];
        #pragma unroll
        for (int mi = 0; mi < 4; ++mi)
            #pragma unroll
            for (int ni = 0; ni < 4; ++ni)
                acc[mi][ni] = __builtin_amdgcn_mfma_f32_16x16x32_bf16(
                    af[mi], bfr[ni], acc[mi][ni], 0, 0, 0);
        __syncthreads();   // drains prefetch + WAR-protects cur
    }

    // C/D layout: col = lane&15, row = quad*4 + reg  [measured m89/m91]
    const int bm = bmT * 128, bn = bnT * 128;
    #pragma unroll
    for (int mi = 0; mi < 4; ++mi) {
        int row = bm + wm + mi * 16 + quad * 4;
        #pragma unroll
        for (int ni = 0; ni < 4; ++ni) {
            int col = bn + wn + ni * 16 + l15;
            float bv = (col < 256) ? biasLo[col] : biasHi[col - 256];
            #pragma unroll
            for (int r = 0; r < 4; ++r) {
                int rr = row + r;
                if (rr < Mstore)
                    C[(size_t)rr * 512 + col] = f2bf(acc[mi][ni][r] + bv);
            }
        }
    }
}

// standalone GEMM (layer 2)
__global__ __launch_bounds__(256) void gemm_bf16_kernel(
    const short* __restrict__ A, const short* __restrict__ B,
    short* __restrict__ C,
    const float* __restrict__ biasLo, const float* __restrict__ biasHi,
    int Mstore, int Kp)
{
    gemm_body(blockIdx.x, A, B, C, biasLo, biasHi, Mstore, Kp);
}

// merged: GEMM layer 1 blocks [0,940) + edge_scatter blocks [940, 940+NB_CNT)
__global__ __launch_bounds__(256) void gemm1_scatter_kernel(
    const short* __restrict__ A, const short* __restrict__ B,
    short* __restrict__ C,
    const float* __restrict__ biasLo, const float* __restrict__ biasHi,
    const int* __restrict__ ei, int* __restrict__ cursor, int* __restrict__ srcs)
{
    const int b = blockIdx.x;
    if (b < NB_GEMM) {
        gemm_body(b, A, B, C, biasLo, biasHi, N_NODES, KP1);
    } else {
        int e = (b - NB_GEMM) * 256 + threadIdx.x;
        if (e >= E_TOT) return;
        int src, dst;
        if (e < N_EDGES) { src = ei[e]; dst = ei[N_EDGES + e]; }
        else { src = e - N_EDGES; dst = src; }
        int pos = atomicAdd(&cursor[dst], 1);
        srcs[pos] = src;
    }
}

// ---------------- CSR scan (single block) ----------------
__global__ __launch_bounds__(1024) void scan_kernel(const int* __restrict__ counts,
                                                    int* __restrict__ offs,
                                                    int* __restrict__ cursor) {
    __shared__ int wsum[16];
    int t = threadIdx.x;
    int lane = t & 63, wv = t >> 6;
    int base = t * 32;
    int local[32];
    int s = 0;
    #pragma unroll
    for (int j = 0; j < 32; ++j) {
        int i = base + j;
        int c = (i < N_NODES) ? counts[i] : 0;
        local[j] = s;
        s += c;
    }
    int incl = s;
    #pragma unroll
    for (int off = 1; off < 64; off <<= 1) {
        int v = __shfl_up(incl, off, 64);
        if (lane >= off) incl += v;
    }
    if (lane == 63) wsum[wv] = incl;
    __syncthreads();
    if (t == 0) {
        int run = 0;
        #pragma unroll
        for (int w2 = 0; w2 < 16; ++w2) { int v = wsum[w2]; wsum[w2] = run; run += v; }
        offs[N_NODES] = run;
    }
    __syncthreads();
    int thrExc = wsum[wv] + incl - s;
    #pragma unroll
    for (int j = 0; j < 32; ++j) {
        int i = base + j;
        if (i < N_NODES) {
            int o = thrExc + local[j];
            offs[i] = o;
            cursor[i] = o;
        }
    }
}

// ---------------- layer-1 fused logits+softmax+aggregate (all nodes) ----------------
__global__ __launch_bounds__(256) void fused_aggr1_kernel(
    const int* __restrict__ offs, const int* __restrict__ srcs,
    const short* __restrict__ C, const float* __restrict__ att,
    const float* __restrict__ bias, short* __restrict__ h1b)
{
    int wid = (int)((blockIdx.x * 256 + threadIdx.x) >> 6);
    int lane = threadIdx.x & 63;
    if (wid >= N_NODES) return;
    int n = wid;
    int half = lane >> 5;
    int l5 = lane & 31;
    int d0 = l5 * 8;
    float attv[8], xr[8];
    {
        float4 aa = *(const float4*)(att + d0);
        float4 ab = *(const float4*)(att + d0 + 4);
        attv[0]=aa.x; attv[1]=aa.y; attv[2]=aa.z; attv[3]=aa.w;
        attv[4]=ab.x; attv[5]=ab.y; attv[6]=ab.z; attv[7]=ab.w;
        bf16x8 xv = *(const bf16x8*)(C + (size_t)n * 512 + 256 + d0);
        #pragma unroll
        for (int j = 0; j < 8; ++j) xr[j] = bf2f(xv[j]);
    }
    float a[8] = {};
    float den = 0.f;
    int beg = offs[n], end = offs[n + 1];
    for (int i = beg; i < end; i += 8) {
        bool act[4];
        int ss[4];
        bf16x8 xlv[4];
        #pragma unroll
        for (int u = 0; u < 4; ++u) {
            int idx = i + 2 * u + half;
            act[u] = idx < end;
            ss[u] = srcs[act[u] ? idx : (end - 1)];
        }
        #pragma unroll
        for (int u = 0; u < 4; ++u)
            xlv[u] = *(const bf16x8*)(C + (size_t)ss[u] * 512 + d0);
        #pragma unroll
        for (int u = 0; u < 4; ++u) {
            float xl[8];
            #pragma unroll
            for (int j = 0; j < 8; ++j) xl[j] = bf2f(xlv[u][j]);
            float p = 0.f;
            #pragma unroll
            for (int j = 0; j < 8; ++j) p += lrelu(xl[j] + xr[j]) * attv[j];
            p += __shfl_xor(p, 1, 64);
            p += __shfl_xor(p, 2, 64);
            p += __shfl_xor(p, 4, 64);
            float wgt = act[u] ? __expf(p) : 0.f;
            den += wgt;
            #pragma unroll
            for (int j = 0; j < 8; ++j) a[j] += wgt * xl[j];
        }
    }
    den += __shfl_xor(den, 32, 64);
    #pragma unroll
    for (int j = 0; j < 8; ++j) a[j] += __shfl_xor(a[j], 32, 64);
    if (half == 0) {
        float inv = 1.f / (den + 1e-16f);
        bf16x8 o;
        #pragma unroll
        for (int j = 0; j < 8; ++j) o[j] = f2bf(elu1(a[j] * inv + bias[d0 + j]));
        // A'2 layout: [n>>7][kchunk=l5][n&127][8]
        *(bf16x8*)(h1b + (size_t)(n >> 7) * TS2 + (size_t)l5 * 1024 + (size_t)(n & 127) * 8) = o;
    }
}

// ---------------- layer-2 fused, SELECTED NODES ONLY ----------------
// R6: head only reads h2[sel[b]] -- so layer-2 softmax-aggregation runs for
// the 4096 batch rows instead of all 30000 nodes (7.3x less gather traffic).
// One wave per batch row; duplicates in sel recompute independently.
// Output compact: h2c[b][256] f32.
__global__ __launch_bounds__(256) void fused_aggr2_sel_kernel(
    const int* __restrict__ offs, const int* __restrict__ srcs,
    const short* __restrict__ C, const float* __restrict__ att,
    const float* __restrict__ bias, const int* __restrict__ sel,
    float* __restrict__ h2c)
{
    int wid = (int)((blockIdx.x * 256 + threadIdx.x) >> 6);
    int lane = threadIdx.x & 63;
    if (wid >= BQ) return;
    int n = sel[wid];
    int half = lane >> 5;
    int l5 = lane & 31;
    int d0 = l5 * 8;
    float attv[8], xr[8];
    {
        float4 aa = *(const float4*)(att + d0);
        float4 ab = *(const float4*)(att + d0 + 4);
        attv[0]=aa.x; attv[1]=aa.y; attv[2]=aa.z; attv[3]=aa.w;
        attv[4]=ab.x; attv[5]=ab.y; attv[6]=ab.z; attv[7]=ab.w;
        bf16x8 xv = *(const bf16x8*)(C + (size_t)n * 512 + 256 + d0);
        #pragma unroll
        for (int j = 0; j < 8; ++j) xr[j] = bf2f(xv[j]);
    }
    float a[8] = {};
    float den = 0.f;
    int beg = offs[n], end = offs[n + 1];
    for (int i = beg; i < end; i += 8) {
        bool act[4];
        int ss[4];
        bf16x8 xlv[4];
        #pragma unroll
        for (int u = 0; u < 4; ++u) {
            int idx = i + 2 * u + half;
            act[u] = idx < end;
            ss[u] = srcs[act[u] ? idx : (end - 1)];
        }
        #pragma unroll
        for (int u = 0; u < 4; ++u)
            xlv[u] = *(const bf16x8*)(C + (size_t)ss[u] * 512 + d0);
        #pragma unroll
        for (int u = 0; u < 4; ++u) {
            float xl[8];
            #pragma unroll
            for (int j = 0; j < 8; ++j) xl[j] = bf2f(xlv[u][j]);
            float p = 0.f;
            #pragma unroll
            for (int j = 0; j < 8; ++j) p += lrelu(xl[j] + xr[j]) * attv[j];
            p += __shfl_xor(p, 1, 64);
            p += __shfl_xor(p, 2, 64);
            p += __shfl_xor(p, 4, 64);
            p += __shfl_xor(p, 8, 64);
            p += __shfl_xor(p, 16, 64);
            float wgt = act[u] ? __expf(p) : 0.f;
            den += wgt;
            #pragma unroll
            for (int j = 0; j < 8; ++j) a[j] += wgt * xl[j];
        }
    }
    den += __shfl_xor(den, 32, 64);
    #pragma unroll
    for (int j = 0; j < 8; ++j) a[j] += __shfl_xor(a[j], 32, 64);
    if (half == 0) {
        float inv = 1.f / (den + 1e-16f);
        float4 o0, o1;
        o0.x = elu1(a[0] * inv + bias[d0 + 0]);
        o0.y = elu1(a[1] * inv + bias[d0 + 1]);
        o0.z = elu1(a[2] * inv + bias[d0 + 2]);
        o0.w = elu1(a[3] * inv + bias[d0 + 3]);
        o1.x = elu1(a[4] * inv + bias[d0 + 4]);
        o1.y = elu1(a[5] * inv + bias[d0 + 5]);
        o1.z = elu1(a[6] * inv + bias[d0 + 6]);
        o1.w = elu1(a[7] * inv + bias[d0 + 7]);
        *(float4*)(h2c + (size_t)wid * 256 + d0) = o0;
        *(float4*)(h2c + (size_t)wid * 256 + d0 + 4) = o1;
    }
}

// ---------------- MLP head: one block (128 thr) per batch row ----------------
__global__ __launch_bounds__(128) void head_mlp_kernel(
    const float* __restrict__ h2c, const int* __restrict__ sel,
    const float* __restrict__ wt, const float* __restrict__ mut,
    const float* __restrict__ W1, const float* __restrict__ b1,
    const float* __restrict__ W2, const float* __restrict__ b2,
    const float* __restrict__ W3, const float* __restrict__ b3,
    float* __restrict__ out)
{
    __shared__ float comb[296];
    __shared__ float z1[128];
    int b = blockIdx.x;
    int t = threadIdx.x;
    const float* hrow = h2c + (size_t)b * 256;   // compact, batch-indexed
    comb[t] = hrow[t];
    comb[128 + t] = hrow[128 + t];
    if (t < 40) comb[256 + t] = (t < 20) ? wt[b * 20 + t] : mut[b * 20 + t - 20];
    __syncthreads();
    float s = b1[t];
    #pragma unroll 8
    for (int i = 0; i < 296; ++i) s += comb[i] * W1[i * 128 + t];
    z1[t] = fmaxf(s, 0.f);
    __syncthreads();
    if (t < 64) {
        float s2 = b2[t];
        #pragma unroll 8
        for (int i = 0; i < 128; ++i) s2 += z1[i] * W2[i * 64 + t];
        float v = fmaxf(s2, 0.f) * W3[t];
        #pragma unroll
        for (int off = 32; off > 0; off >>= 1) v += __shfl_xor(v, off, 64);
        if (t == 0) out[b] = v + b3[0];
    }
}

// ---------------- launch ----------------
extern "C" void kernel_launch(void* const* d_in, const int* in_sizes, int n_in,
                              void* d_out, int out_size, void* d_ws, size_t ws_size,
                              hipStream_t stream) {
    const float* x     = (const float*)d_in[0];
    const int*   ei    = (const int*)  d_in[1];
    const int*   sel   = (const int*)  d_in[2];
    const float* wt    = (const float*)d_in[3];
    const float* mut   = (const float*)d_in[4];
    const float* Wl1   = (const float*)d_in[5];
    const float* bl1   = (const float*)d_in[6];
    const float* Wr1   = (const float*)d_in[7];
    const float* br1   = (const float*)d_in[8];
    const float* att1  = (const float*)d_in[9];
    const float* bias1 = (const float*)d_in[10];
    const float* Wl2   = (const float*)d_in[11];
    const float* bl2   = (const float*)d_in[12];
    const float* Wr2   = (const float*)d_in[13];
    const float* br2   = (const float*)d_in[14];
    const float* att2  = (const float*)d_in[15];
    const float* bias2 = (const float*)d_in[16];
    const float* hW1   = (const float*)d_in[17];
    const float* hb1   = (const float*)d_in[18];
    const float* hW2   = (const float*)d_in[19];
    const float* hb2   = (const float*)d_in[20];
    const float* hW3   = (const float*)d_in[21];
    const float* hb3   = (const float*)d_in[22];
    float* out = (float*)d_out;

    // workspace layout (256B-aligned chunks)
    char* w = (char*)d_ws;
    size_t off = 0;
    auto alloc = [&](size_t bytes) -> void* {
        void* p = w + off;
        off += (bytes + 255) & ~(size_t)255;
        return p;
    };
    short* Abf    = (short*)alloc((size_t)NBM * TS1 * 2);       // x in A'-tiles; reused as C2 (bf16)
    short* Wbf    = (short*)alloc((size_t)4 * TS1 * 2);         // [Wl1|Wr1] in B'-tiles
    short* C1b    = (short*)alloc((size_t)N_NODES * 512 * 2);   // [xl1|xr1] bf16; reused as h2c f32
    int*   counts = (int*)  alloc((size_t)N_NODES * 4);
    int*   cursor = (int*)  alloc((size_t)N_NODES * 4);
    int*   offs   = (int*)  alloc((size_t)(N_NODES + 1) * 4);
    int*   srcs   = (int*)  alloc((size_t)E_TOT * 4);
    short* H1bf   = (short*)alloc((size_t)NBM * TS2 * 2);       // h1 in A'-tiles (GEMM2 A)
    short* W2bf   = (short*)alloc((size_t)4 * TS2 * 2);         // [Wl2|Wr2] in B'-tiles
    short* C2b = Abf;          // [xl2|xr2] bf16 overlays dead x-tiles
    float* h2c = (float*)C1b;  // compact h2 (4096x256 f32) overlays dead C1b
    (void)in_sizes; (void)n_in; (void)out_size; (void)ws_size;

    hipMemsetAsync(counts, 0, (size_t)N_NODES * 4, stream);

    // K1: pack_x | pack_w(L1) | pack_w(L2) | edge_count
    prep_kernel<<<NB_PREP, 256, 0, stream>>>(x, Abf, Wl1, Wr1, Wbf, Wl2, Wr2, W2bf, ei, counts);
    // K2: scan
    scan_kernel<<<1, 1024, 0, stream>>>(counts, offs, cursor);
    // K3: GEMM layer 1 (double-buffered) | edge_scatter
    gemm1_scatter_kernel<<<NB_GEMM + NB_CNT, 256, 0, stream>>>(
        Abf, Wbf, C1b, bl1, br1, ei, cursor, srcs);
    // K4: layer-1 aggregate (all nodes)
    fused_aggr1_kernel<<<(N_NODES + 3) / 4, 256, 0, stream>>>(offs, srcs, C1b, att1, bias1, H1bf);
    // K5: GEMM layer 2 (double-buffered)
    gemm_bf16_kernel<<<NB_GEMM, 256, 0, stream>>>(H1bf, W2bf, C2b, bl2, br2, N_NODES, 256);
    // K6: layer-2 aggregate, selected nodes only (4096 waves)
    fused_aggr2_sel_kernel<<<(BQ + 3) / 4, 256, 0, stream>>>(offs, srcs, C2b, att2, bias2, sel, h2c);
    // K7: head
    head_mlp_kernel<<<BQ, 128, 0, stream>>>(h2c, sel, wt, mut, hW1, hb1, hW2, hb2, hW3, hb3, out);
}

// Round 7
// 517.526 us; speedup vs baseline: 1.1620x; 1.0390x over previous
//
#include <hip/hip_runtime.h>

// ---------------- problem constants ----------------
#define N_NODES 30000
#define N_EDGES 480000
#define E_TOT   510000        // edges + self loops
#define BQ      4096
#define IN_DIM  1281
#define KP1     1344          // 1281 padded to mult of 64 (pack tile) & 32 (gemm)
#define NKG     (KP1/64)      // 21 col-groups in pack_x
#define MP      30080         // 30000 padded to mult of 128
#define NBM     235           // MP/128
#define TS1     (KP1*128)     // A'/B' tile stride (shorts), layer 1
#define TS2     (256*128)     // tile stride, layer 2

// merged-grid block counts
#define NB_PX   (NBM*NKG)         // 4935 pack_x blocks
#define NB_PW1  ((KP1/8)*4)       // 672 pack_w layer-1 blocks
#define NB_PW2  ((256/8)*4)       // 128 pack_w layer-2 blocks
#define NB_CNT  ((E_TOT+255)/256) // 1993 edge_count / scatter blocks
#define NB_PREP (NB_PX+NB_PW1+NB_PW2+NB_CNT)
#define NB_GEMM 940               // NBM*4 tiles (128x128)

typedef __attribute__((ext_vector_type(8))) short bf16x8;
typedef __attribute__((ext_vector_type(4))) short bf16x4;
typedef __attribute__((ext_vector_type(4))) float f32x4;

__device__ __forceinline__ short f2bf(float f) {
    unsigned int u = __builtin_bit_cast(unsigned int, f);
    u += 0x7fffu + ((u >> 16) & 1u);       // RNE
    return (short)(u >> 16);
}

__device__ __forceinline__ float bf2f(short s) {
    unsigned int u = ((unsigned int)(unsigned short)s) << 16;
    return __builtin_bit_cast(float, u);
}

__device__ __forceinline__ void async16(void* lds, const void* g) {
    __builtin_amdgcn_global_load_lds(
        (const __attribute__((address_space(1))) void*)g,
        (__attribute__((address_space(3))) void*)lds, 16, 0, 0);
}

__device__ __forceinline__ float elu1(float x) {
    return x > 0.f ? x : __expf(x) - 1.f;
}

__device__ __forceinline__ float lrelu(float x) {
    return x > 0.f ? x : 0.2f * x;
}

// ---------------- pack bodies (device functions) ----------------
// x (30000x1281 f32) -> A' tile-major: A'[mt][kchunk][m&127][k&7] bf16.
// R7: 16 B/lane global reads. Rows are 4B-aligned (stride 5124 B) so typed
// float4 is illegal; __builtin_memcpy lets the compiler emit a legal
// 4B-aligned dwordx4. Lane = (rq=lane>>4, cq=lane&15): 1 row x 4 cols per
// load, 8 loads/thread, all hoisted before convert (8 in flight).
__device__ __forceinline__ void pack_x_body(int mt, int kg, short* L /*[128][72]*/,
                                            const float* __restrict__ x,
                                            short* __restrict__ A) {
    short (*Lx)[72] = (short(*)[72])L;
    const int t = threadIdx.x;
    const int wave = t >> 6, lane = t & 63;
    const int rq = lane >> 4;        // 0..3
    const int cq = lane & 15;        // 0..15
    const int m0 = mt * 128;
    const int c0 = kg * 64 + cq * 4;
    float4 v[8];
    #pragma unroll
    for (int j = 0; j < 8; ++j) {
        int ml = j * 16 + wave * 4 + rq;
        int m = m0 + ml;
        v[j] = make_float4(0.f, 0.f, 0.f, 0.f);
        if (m < N_NODES) {
            const float* p = x + (size_t)m * IN_DIM + c0;
            if (c0 + 3 < IN_DIM) {
                __builtin_memcpy(&v[j], p, 16);   // 4B-aligned vector load
            } else {                              // kg tail (cols >= 1280)
                float tmp[4] = {0.f, 0.f, 0.f, 0.f};
                #pragma unroll
                for (int e = 0; e < 4; ++e)
                    if (c0 + e < IN_DIM) tmp[e] = p[e];
                v[j] = make_float4(tmp[0], tmp[1], tmp[2], tmp[3]);
            }
        }
    }
    #pragma unroll
    for (int j = 0; j < 8; ++j) {
        int ml = j * 16 + wave * 4 + rq;
        bf16x4 sv;
        sv[0] = f2bf(v[j].x); sv[1] = f2bf(v[j].y);
        sv[2] = f2bf(v[j].z); sv[3] = f2bf(v[j].w);
        *(bf16x4*)&Lx[ml][cq * 4] = sv;           // 8 B LDS store
    }
    __syncthreads();
    short* Atile = A + (size_t)mt * TS1 + (size_t)kg * 8 * 1024;
    #pragma unroll
    for (int pass = 0; pass < 4; ++pass) {
        int u = pass * 256 + t;          // 0..1023
        int tc = u >> 7, ml = u & 127;   // tc 0..7 (this block's 8 kchunks)
        *(bf16x8*)(Atile + (size_t)tc * 1024 + ml * 8) = *(const bf16x8*)&Lx[ml][tc * 8];
    }
}

// W (K x 256 row-major, Wl|Wr) -> B'[bt][kchunk][n&127][k&7]; k-pad zeroed.
__device__ __forceinline__ void pack_w_body(int kc, int bt, short* L /*[8][128]*/,
                                            const float* __restrict__ Wl,
                                            const float* __restrict__ Wr,
                                            short* __restrict__ Bt,
                                            int K, int Kp) {
    short (*Lw)[128] = (short(*)[128])L;
    const int t = threadIdx.x;
    const float* W = (bt < 2) ? Wl : Wr;
    const int ncol0 = (bt & 1) * 128;
    #pragma unroll
    for (int pass = 0; pass < 4; ++pass) {
        int u = pass * 256 + t;               // 1024 elems: k_r = u>>7, n_l = u&127
        int k_r = u >> 7, n_l = u & 127;
        int k = kc * 8 + k_r;
        Lw[k_r][n_l] = (k < K) ? f2bf(W[(size_t)k * 256 + ncol0 + n_l]) : (short)0;
    }
    __syncthreads();
    if (t < 128) {
        bf16x8 v;
        #pragma unroll
        for (int j = 0; j < 8; ++j) v[j] = Lw[j][t];
        *(bf16x8*)(Bt + (size_t)bt * ((size_t)Kp * 128) + (size_t)kc * 1024 + (size_t)t * 8) = v;
    }
}

// ---------------- merged prep: pack_x | pack_w(L1) | pack_w(L2) | edge_count ----------------
__global__ __launch_bounds__(256) void prep_kernel(
    const float* __restrict__ x, short* __restrict__ A,
    const float* __restrict__ Wl1, const float* __restrict__ Wr1, short* __restrict__ Wbf,
    const float* __restrict__ Wl2, const float* __restrict__ Wr2, short* __restrict__ W2bf,
    const int* __restrict__ ei, int* __restrict__ counts)
{
    __shared__ short L[128 * 72];
    const int b = blockIdx.x;
    if (b < NB_PX) {
        pack_x_body(b / NKG, b % NKG, L, x, A);   // slab-major order
    } else if (b < NB_PX + NB_PW1) {
        int r = b - NB_PX;
        pack_w_body(r % (KP1 / 8), r / (KP1 / 8), L, Wl1, Wr1, Wbf, IN_DIM, KP1);
    } else if (b < NB_PX + NB_PW1 + NB_PW2) {
        int r = b - NB_PX - NB_PW1;
        pack_w_body(r % (256 / 8), r / (256 / 8), L, Wl2, Wr2, W2bf, 256, 256);
    } else {
        int r = b - NB_PX - NB_PW1 - NB_PW2;
        int e = r * 256 + threadIdx.x;
        if (e < E_TOT) {
            int dst = (e < N_EDGES) ? ei[N_EDGES + e] : (e - N_EDGES);
            atomicAdd(&counts[dst], 1);
        }
    }
}

// ---------------- bf16 MFMA GEMM, 128x128 tile ----------------
// R7: A double-buffered in LDS (async16); B fragments read DIRECTLY from
// global each iter -- B' is small (2.8 MB / 0.26 MB) and L2-resident, and its
// tiled layout already equals the fragment layout (aligned 16 B per lane).
// Halves ds_read traffic, halves async16 count, halves LDS (16 KB) -> more
// blocks/CU; whole 940-block grid is single-round resident.
__device__ __forceinline__ void gemm_body(
    int id,
    const short* __restrict__ A, const short* __restrict__ B,
    short* __restrict__ C,
    const float* __restrict__ biasLo, const float* __restrict__ biasHi,
    int Mstore, int Kp)
{
    __shared__ short As[2][4096];   // [buf][4 kc][128 m][8 k]
    int bmT, bnT;
    if (id < 928) { int grp = id >> 5, w32 = id & 31; bmT = grp * 8 + (w32 & 7); bnT = w32 >> 3; }
    else          { int r = id - 928;  bmT = 232 + (r >> 2); bnT = r & 3; }
    const int tid  = threadIdx.x;
    const int wave = tid >> 6;
    const int lane = tid & 63;
    const int l15  = lane & 15;
    const int quad = lane >> 4;

    const size_t tstride = (size_t)Kp * 128;
    const short* aPtr = A + (size_t)bmT * tstride + wave * 1024 + lane * 8;
    const short* bBase = B + (size_t)bnT * tstride + quad * 1024;

    const int wm = (wave & 1) * 64;
    const int wn = (wave >> 1) * 64;

    f32x4 acc[4][4] = {};
    const int nt = Kp / 32;

    // prologue: stage A tile 0 into buffer 0
    async16(&As[0][wave * 1024],       aPtr);
    async16(&As[0][wave * 1024 + 512], aPtr + 512);
    aPtr += 4096;
    __syncthreads();

    for (int it = 0; it < nt; ++it) {
        const int cur = it & 1, nxt = cur ^ 1;
        if (it + 1 < nt) {
            async16(&As[nxt][wave * 1024],       aPtr);
            async16(&As[nxt][wave * 1024 + 512], aPtr + 512);
            aPtr += 4096;
        }
        // B fragments straight from global (L2-hot, layout == fragment layout)
        const short* bG = bBase + (size_t)it * 4096;
        bf16x8 bfr[4], af[4];
        #pragma unroll
        for (int i = 0; i < 4; ++i)
            bfr[i] = *(const bf16x8*)&bG[(wn + i * 16 + l15) * 8];
        #pragma unroll
        for (int i = 0; i < 4; ++i)
            af[i] = *(const bf16x8*)&As[cur][quad * 1024 + (wm + i * 16 + l15) * 8];
        #pragma unroll
        for (int ni = 0; ni < 4; ++ni)
            #pragma unroll
            for (int mi = 0; mi < 4; ++mi)
                acc[mi][ni] = __builtin_amdgcn_mfma_f32_16x16x32_bf16(
                    af[mi], bfr[ni], acc[mi][ni], 0, 0, 0);
        __syncthreads();   // drains A prefetch + WAR-protects cur
    }

    // C/D layout: col = lane&15, row = quad*4 + reg  [measured m89/m91]
    const int bm = bmT * 128, bn = bnT * 128;
    #pragma unroll
    for (int mi = 0; mi < 4; ++mi) {
        int row = bm + wm + mi * 16 + quad * 4;
        #pragma unroll
        for (int ni = 0; ni < 4; ++ni) {
            int col = bn + wn + ni * 16 + l15;
            float bv = (col < 256) ? biasLo[col] : biasHi[col - 256];
            #pragma unroll
            for (int r = 0; r < 4; ++r) {
                int rr = row + r;
                if (rr < Mstore)
                    C[(size_t)rr * 512 + col] = f2bf(acc[mi][ni][r] + bv);
            }
        }
    }
}

// standalone GEMM (layer 2)
__global__ __launch_bounds__(256) void gemm_bf16_kernel(
    const short* __restrict__ A, const short* __restrict__ B,
    short* __restrict__ C,
    const float* __restrict__ biasLo, const float* __restrict__ biasHi,
    int Mstore, int Kp)
{
    gemm_body(blockIdx.x, A, B, C, biasLo, biasHi, Mstore, Kp);
}

// merged: GEMM layer 1 blocks [0,940) + edge_scatter blocks [940, 940+NB_CNT)
__global__ __launch_bounds__(256) void gemm1_scatter_kernel(
    const short* __restrict__ A, const short* __restrict__ B,
    short* __restrict__ C,
    const float* __restrict__ biasLo, const float* __restrict__ biasHi,
    const int* __restrict__ ei, int* __restrict__ cursor, int* __restrict__ srcs)
{
    const int b = blockIdx.x;
    if (b < NB_GEMM) {
        gemm_body(b, A, B, C, biasLo, biasHi, N_NODES, KP1);
    } else {
        int e = (b - NB_GEMM) * 256 + threadIdx.x;
        if (e >= E_TOT) return;
        int src, dst;
        if (e < N_EDGES) { src = ei[e]; dst = ei[N_EDGES + e]; }
        else { src = e - N_EDGES; dst = src; }
        int pos = atomicAdd(&cursor[dst], 1);
        srcs[pos] = src;
    }
}

// ---------------- CSR scan (single block) ----------------
__global__ __launch_bounds__(1024) void scan_kernel(const int* __restrict__ counts,
                                                    int* __restrict__ offs,
                                                    int* __restrict__ cursor) {
    __shared__ int wsum[16];
    int t = threadIdx.x;
    int lane = t & 63, wv = t >> 6;
    int base = t * 32;
    int local[32];
    int s = 0;
    #pragma unroll
    for (int j = 0; j < 32; ++j) {
        int i = base + j;
        int c = (i < N_NODES) ? counts[i] : 0;
        local[j] = s;
        s += c;
    }
    int incl = s;
    #pragma unroll
    for (int off = 1; off < 64; off <<= 1) {
        int v = __shfl_up(incl, off, 64);
        if (lane >= off) incl += v;
    }
    if (lane == 63) wsum[wv] = incl;
    __syncthreads();
    if (t == 0) {
        int run = 0;
        #pragma unroll
        for (int w2 = 0; w2 < 16; ++w2) { int v = wsum[w2]; wsum[w2] = run; run += v; }
        offs[N_NODES] = run;
    }
    __syncthreads();
    int thrExc = wsum[wv] + incl - s;
    #pragma unroll
    for (int j = 0; j < 32; ++j) {
        int i = base + j;
        if (i < N_NODES) {
            int o = thrExc + local[j];
            offs[i] = o;
            cursor[i] = o;
        }
    }
}

// ---------------- layer-1 fused logits+softmax+aggregate (all nodes) ----------------
__global__ __launch_bounds__(256) void fused_aggr1_kernel(
    const int* __restrict__ offs, const int* __restrict__ srcs,
    const short* __restrict__ C, const float* __restrict__ att,
    const float* __restrict__ bias, short* __restrict__ h1b)
{
    int wid = (int)((blockIdx.x * 256 + threadIdx.x) >> 6);
    int lane = threadIdx.x & 63;
    if (wid >= N_NODES) return;
    int n = wid;
    int half = lane >> 5;
    int l5 = lane & 31;
    int d0 = l5 * 8;
    float attv[8], xr[8];
    {
        float4 aa = *(const float4*)(att + d0);
        float4 ab = *(const float4*)(att + d0 + 4);
        attv[0]=aa.x; attv[1]=aa.y; attv[2]=aa.z; attv[3]=aa.w;
        attv[4]=ab.x; attv[5]=ab.y; attv[6]=ab.z; attv[7]=ab.w;
        bf16x8 xv = *(const bf16x8*)(C + (size_t)n * 512 + 256 + d0);
        #pragma unroll
        for (int j = 0; j < 8; ++j) xr[j] = bf2f(xv[j]);
    }
    float a[8] = {};
    float den = 0.f;
    int beg = offs[n], end = offs[n + 1];
    for (int i = beg; i < end; i += 8) {
        bool act[4];
        int ss[4];
        bf16x8 xlv[4];
        #pragma unroll
        for (int u = 0; u < 4; ++u) {
            int idx = i + 2 * u + half;
            act[u] = idx < end;
            ss[u] = srcs[act[u] ? idx : (end - 1)];
        }
        #pragma unroll
        for (int u = 0; u < 4; ++u)
            xlv[u] = *(const bf16x8*)(C + (size_t)ss[u] * 512 + d0);
        #pragma unroll
        for (int u = 0; u < 4; ++u) {
            float xl[8];
            #pragma unroll
            for (int j = 0; j < 8; ++j) xl[j] = bf2f(xlv[u][j]);
            float p = 0.f;
            #pragma unroll
            for (int j = 0; j < 8; ++j) p += lrelu(xl[j] + xr[j]) * attv[j];
            p += __shfl_xor(p, 1, 64);
            p += __shfl_xor(p, 2, 64);
            p += __shfl_xor(p, 4, 64);
            float wgt = act[u] ? __expf(p) : 0.f;
            den += wgt;
            #pragma unroll
            for (int j = 0; j < 8; ++j) a[j] += wgt * xl[j];
        }
    }
    den += __shfl_xor(den, 32, 64);
    #pragma unroll
    for (int j = 0; j < 8; ++j) a[j] += __shfl_xor(a[j], 32, 64);
    if (half == 0) {
        float inv = 1.f / (den + 1e-16f);
        bf16x8 o;
        #pragma unroll
        for (int j = 0; j < 8; ++j) o[j] = f2bf(elu1(a[j] * inv + bias[d0 + j]));
        // A'2 layout: [n>>7][kchunk=l5][n&127][8]
        *(bf16x8*)(h1b + (size_t)(n >> 7) * TS2 + (size_t)l5 * 1024 + (size_t)(n & 127) * 8) = o;
    }
}

// ---------------- layer-2 fused, SELECTED NODES ONLY ----------------
__global__ __launch_bounds__(256) void fused_aggr2_sel_kernel(
    const int* __restrict__ offs, const int* __restrict__ srcs,
    const short* __restrict__ C, const float* __restrict__ att,
    const float* __restrict__ bias, const int* __restrict__ sel,
    float* __restrict__ h2c)
{
    int wid = (int)((blockIdx.x * 256 + threadIdx.x) >> 6);
    int lane = threadIdx.x & 63;
    if (wid >= BQ) return;
    int n = sel[wid];
    int half = lane >> 5;
    int l5 = lane & 31;
    int d0 = l5 * 8;
    float attv[8], xr[8];
    {
        float4 aa = *(const float4*)(att + d0);
        float4 ab = *(const float4*)(att + d0 + 4);
        attv[0]=aa.x; attv[1]=aa.y; attv[2]=aa.z; attv[3]=aa.w;
        attv[4]=ab.x; attv[5]=ab.y; attv[6]=ab.z; attv[7]=ab.w;
        bf16x8 xv = *(const bf16x8*)(C + (size_t)n * 512 + 256 + d0);
        #pragma unroll
        for (int j = 0; j < 8; ++j) xr[j] = bf2f(xv[j]);
    }
    float a[8] = {};
    float den = 0.f;
    int beg = offs[n], end = offs[n + 1];
    for (int i = beg; i < end; i += 8) {
        bool act[4];
        int ss[4];
        bf16x8 xlv[4];
        #pragma unroll
        for (int u = 0; u < 4; ++u) {
            int idx = i + 2 * u + half;
            act[u] = idx < end;
            ss[u] = srcs[act[u] ? idx : (end - 1)];
        }
        #pragma unroll
        for (int u = 0; u < 4; ++u)
            xlv[u] = *(const bf16x8*)(C + (size_t)ss[u] * 512 + d0);
        #pragma unroll
        for (int u = 0; u < 4; ++u) {
            float xl[8];
            #pragma unroll
            for (int j = 0; j < 8; ++j) xl[j] = bf2f(xlv[u][j]);
            float p = 0.f;
            #pragma unroll
            for (int j = 0; j < 8; ++j) p += lrelu(xl[j] + xr[j]) * attv[j];
            p += __shfl_xor(p, 1, 64);
            p += __shfl_xor(p, 2, 64);
            p += __shfl_xor(p, 4, 64);
            p += __shfl_xor(p, 8, 64);
            p += __shfl_xor(p, 16, 64);
            float wgt = act[u] ? __expf(p) : 0.f;
            den += wgt;
            #pragma unroll
            for (int j = 0; j < 8; ++j) a[j] += wgt * xl[j];
        }
    }
    den += __shfl_xor(den, 32, 64);
    #pragma unroll
    for (int j = 0; j < 8; ++j) a[j] += __shfl_xor(a[j], 32, 64);
    if (half == 0) {
        float inv = 1.f / (den + 1e-16f);
        float4 o0, o1;
        o0.x = elu1(a[0] * inv + bias[d0 + 0]);
        o0.y = elu1(a[1] * inv + bias[d0 + 1]);
        o0.z = elu1(a[2] * inv + bias[d0 + 2]);
        o0.w = elu1(a[3] * inv + bias[d0 + 3]);
        o1.x = elu1(a[4] * inv + bias[d0 + 4]);
        o1.y = elu1(a[5] * inv + bias[d0 + 5]);
        o1.z = elu1(a[6] * inv + bias[d0 + 6]);
        o1.w = elu1(a[7] * inv + bias[d0 + 7]);
        *(float4*)(h2c + (size_t)wid * 256 + d0) = o0;
        *(float4*)(h2c + (size_t)wid * 256 + d0 + 4) = o1;
    }
}

// ---------------- MLP head: one block (128 thr) per batch row ----------------
__global__ __launch_bounds__(128) void head_mlp_kernel(
    const float* __restrict__ h2c, const int* __restrict__ sel,
    const float* __restrict__ wt, const float* __restrict__ mut,
    const float* __restrict__ W1, const float* __restrict__ b1,
    const float* __restrict__ W2, const float* __restrict__ b2,
    const float* __restrict__ W3, const float* __restrict__ b3,
    float* __restrict__ out)
{
    __shared__ float comb[296];
    __shared__ float z1[128];
    int b = blockIdx.x;
    int t = threadIdx.x;
    const float* hrow = h2c + (size_t)b * 256;   // compact, batch-indexed
    comb[t] = hrow[t];
    comb[128 + t] = hrow[128 + t];
    if (t < 40) comb[256 + t] = (t < 20) ? wt[b * 20 + t] : mut[b * 20 + t - 20];
    __syncthreads();
    float s = b1[t];
    #pragma unroll 8
    for (int i = 0; i < 296; ++i) s += comb[i] * W1[i * 128 + t];
    z1[t] = fmaxf(s, 0.f);
    __syncthreads();
    if (t < 64) {
        float s2 = b2[t];
        #pragma unroll 8
        for (int i = 0; i < 128; ++i) s2 += z1[i] * W2[i * 64 + t];
        float v = fmaxf(s2, 0.f) * W3[t];
        #pragma unroll
        for (int off = 32; off > 0; off >>= 1) v += __shfl_xor(v, off, 64);
        if (t == 0) out[b] = v + b3[0];
    }
}

// ---------------- launch ----------------
extern "C" void kernel_launch(void* const* d_in, const int* in_sizes, int n_in,
                              void* d_out, int out_size, void* d_ws, size_t ws_size,
                              hipStream_t stream) {
    const float* x     = (const float*)d_in[0];
    const int*   ei    = (const int*)  d_in[1];
    const int*   sel   = (const int*)  d_in[2];
    const float* wt    = (const float*)d_in[3];
    const float* mut   = (const float*)d_in[4];
    const float* Wl1   = (const float*)d_in[5];
    const float* bl1   = (const float*)d_in[6];
    const float* Wr1   = (const float*)d_in[7];
    const float* br1   = (const float*)d_in[8];
    const float* att1  = (const float*)d_in[9];
    const float* bias1 = (const float*)d_in[10];
    const float* Wl2   = (const float*)d_in[11];
    const float* bl2   = (const float*)d_in[12];
    const float* Wr2   = (const float*)d_in[13];
    const float* br2   = (const float*)d_in[14];
    const float* att2  = (const float*)d_in[15];
    const float* bias2 = (const float*)d_in[16];
    const float* hW1   = (const float*)d_in[17];
    const float* hb1   = (const float*)d_in[18];
    const float* hW2   = (const float*)d_in[19];
    const float* hb2   = (const float*)d_in[20];
    const float* hW3   = (const float*)d_in[21];
    const float* hb3   = (const float*)d_in[22];
    float* out = (float*)d_out;

    // workspace layout (256B-aligned chunks)
    char* w = (char*)d_ws;
    size_t off = 0;
    auto alloc = [&](size_t bytes) -> void* {
        void* p = w + off;
        off += (bytes + 255) & ~(size_t)255;
        return p;
    };
    short* Abf    = (short*)alloc((size_t)NBM * TS1 * 2);       // x in A'-tiles; reused as C2 (bf16)
    short* Wbf    = (short*)alloc((size_t)4 * TS1 * 2);         // [Wl1|Wr1] in B'-tiles
    short* C1b    = (short*)alloc((size_t)N_NODES * 512 * 2);   // [xl1|xr1] bf16; reused as h2c f32
    int*   counts = (int*)  alloc((size_t)N_NODES * 4);
    int*   cursor = (int*)  alloc((size_t)N_NODES * 4);
    int*   offs   = (int*)  alloc((size_t)(N_NODES + 1) * 4);
    int*   srcs   = (int*)  alloc((size_t)E_TOT * 4);
    short* H1bf   = (short*)alloc((size_t)NBM * TS2 * 2);       // h1 in A'-tiles (GEMM2 A)
    short* W2bf   = (short*)alloc((size_t)4 * TS2 * 2);         // [Wl2|Wr2] in B'-tiles
    short* C2b = Abf;          // [xl2|xr2] bf16 overlays dead x-tiles
    float* h2c = (float*)C1b;  // compact h2 (4096x256 f32) overlays dead C1b
    (void)in_sizes; (void)n_in; (void)out_size; (void)ws_size;

    hipMemsetAsync(counts, 0, (size_t)N_NODES * 4, stream);

    // K1: pack_x | pack_w(L1) | pack_w(L2) | edge_count
    prep_kernel<<<NB_PREP, 256, 0, stream>>>(x, Abf, Wl1, Wr1, Wbf, Wl2, Wr2, W2bf, ei, counts);
    // K2: scan
    scan_kernel<<<1, 1024, 0, stream>>>(counts, offs, cursor);
    // K3: GEMM layer 1 (A-dbuf LDS, B-direct) | edge_scatter
    gemm1_scatter_kernel<<<NB_GEMM + NB_CNT, 256, 0, stream>>>(
        Abf, Wbf, C1b, bl1, br1, ei, cursor, srcs);
    // K4: layer-1 aggregate (all nodes)
    fused_aggr1_kernel<<<(N_NODES + 3) / 4, 256, 0, stream>>>(offs, srcs, C1b, att1, bias1, H1bf);
    // K5: GEMM layer 2
    gemm_bf16_kernel<<<NB_GEMM, 256, 0, stream>>>(H1bf, W2bf, C2b, bl2, br2, N_NODES, 256);
    // K6: layer-2 aggregate, selected nodes only (4096 waves)
    fused_aggr2_sel_kernel<<<(BQ + 3) / 4, 256, 0, stream>>>(offs, srcs, C2b, att2, bias2, sel, h2c);
    // K7: head
    head_mlp_kernel<<<BQ, 128, 0, stream>>>(h2c, sel, wt, mut, hW1, hb1, hW2, hb2, hW3, hb3, out);
}